// Round 7
// baseline (264.981 us; speedup 1.0000x reference)
//
#include <hip/hip_runtime.h>
#include <stdint.h>

// Self-attention, B=8 S=2048 D=E=512, fp32 in/out, bf16 MFMA internally.
//   conv:     fused xconv (x fp32->bf16, 4096 blocks) + wconv (W transpose, 192 blocks)
//   qkv_gemm: pipelined double-buffered staging; Q/K use SWAPPED-operand MFMA
//             (acc = C^T in regs) so the epilogue stores coalesced u16x4;
//             V written to 16e x 32s 1KB tiles.
//   attn v7:  v6's counted-vmcnt pipeline on 512 blocks x 4 waves x 32 Q-rows,
//             2 INDEPENDENT blocks/CU -> cross-block latency hiding (one block's
//             compute covers the other's barrier drain). Kt double-buffered,
//             Pl double-buffered, one fused "vmcnt(8) lgkm(0); s_barrier" per iter.

using f32x4 = __attribute__((ext_vector_type(4))) float;
using s16x8 = __attribute__((ext_vector_type(8))) short;
using u16x4 = __attribute__((ext_vector_type(4))) unsigned short;

#define S_LEN 2048
#define EMB   512

#define ASYNC16(g, l)                                                     \
  __builtin_amdgcn_global_load_lds(                                       \
      (const __attribute__((address_space(1))) void*)(g),                 \
      (__attribute__((address_space(3))) void*)(l), 16, 0, 0)

__device__ __forceinline__ unsigned short f2bf(float f) {
  union { float f; unsigned u; } v; v.f = f;
  unsigned r = v.u + 0x7fffu + ((v.u >> 16) & 1u);   // RNE
  return (unsigned short)(r >> 16);
}

// ---------------- kernel 0: fused x-convert + W-transpose ----------------
__global__ __launch_bounds__(256) void conv_kernel(
    const float* __restrict__ x, short* __restrict__ xb,
    const float* __restrict__ Wq, const float* __restrict__ Wk,
    const float* __restrict__ Wv, short* __restrict__ Wt) {
  __shared__ float T[64][65];
  if (blockIdx.x < 4096) {
    int i = (blockIdx.x * 256 + threadIdx.x) * 8;
    f32x4 a = *(const f32x4*)(x + i);
    f32x4 b = *(const f32x4*)(x + i + 4);
    s16x8 h;
    h[0] = (short)f2bf(a[0]); h[1] = (short)f2bf(a[1]);
    h[2] = (short)f2bf(a[2]); h[3] = (short)f2bf(a[3]);
    h[4] = (short)f2bf(b[0]); h[5] = (short)f2bf(b[1]);
    h[6] = (short)f2bf(b[2]); h[7] = (short)f2bf(b[3]);
    *(s16x8*)(xb + i) = h;
  } else {
    int bid = blockIdx.x - 4096;
    int mat = bid >> 6;
    int t   = bid & 63;
    int k0  = (t & 7) << 6, n0 = (t >> 3) << 6;
    const float* W = (mat == 0) ? Wq : (mat == 1) ? Wk : Wv;
    int tid = threadIdx.x;
    int rr = tid >> 4, cc = tid & 15;
#pragma unroll
    for (int p = 0; p < 4; ++p) {
      int row = p * 16 + rr;
      f32x4 v = *(const f32x4*)(W + (size_t)(k0 + row) * 512 + n0 + cc * 4);
#pragma unroll
      for (int j = 0; j < 4; ++j) T[row][cc * 4 + j] = v[j];
    }
    __syncthreads();
    short* D = Wt + (size_t)mat * 262144;
#pragma unroll
    for (int p = 0; p < 4; ++p) {
      int nrow = p * 16 + rr;
      u16x4 h;
#pragma unroll
      for (int j = 0; j < 4; ++j) h[j] = f2bf(T[cc * 4 + j][nrow]);
      *(u16x4*)(D + (size_t)(n0 + nrow) * 512 + k0 + cc * 4) = h;
    }
  }
}

// ---------------- kernel 1: QKV projection GEMM (pipelined, C^T epilogue) ----------------
// mat<2: acc = mfma(bfr, af) = C^T  -> lane holds 4 consecutive-e values -> u16x4 stores.
// mat=2: acc = mfma(af, bfr) = C    -> lane holds 4 consecutive-s values -> V-tile u16x4.
__global__ __launch_bounds__(256) void qkv_gemm(
    const short* __restrict__ xb, const short* __restrict__ Wt,
    const float* __restrict__ bq, const float* __restrict__ bk,
    const float* __restrict__ bv,
    short* __restrict__ Qg, short* __restrict__ Kg, short* __restrict__ VTg) {
  __shared__ __align__(16) short As[2][128 * 64];   // 16B chunk c stored at c^(row&7)
  __shared__ __align__(16) short Bs[2][128 * 64];
  int gid = blockIdx.x;
  int mat = gid >> 9;
  int rem = gid & 511;
  int mt  = rem & 127, nt = rem >> 7;
  int m0  = mt << 7,   n0 = nt << 7;
  const short* W    = Wt + (size_t)mat * 262144;
  const float* bias = (mat == 0) ? bq : (mat == 1) ? bk : bv;

  int tid = threadIdx.x, lane = tid & 63, wv = tid >> 6;
  int l16 = lane & 15, quad = lane >> 4;
  int wr = (wv & 1) << 6, wc = (wv >> 1) << 6;
  int drow = lane >> 3;
  int dchk = (lane & 7) ^ drow;

  const short* asrc[4];
  const short* bsrc[4];
#pragma unroll
  for (int i = 0; i < 4; ++i) {
    int row = (wv * 4 + i) * 8 + drow;
    asrc[i] = xb + (size_t)(m0 + row) * 512 + dchk * 8;
    bsrc[i] = W  + (size_t)(n0 + row) * 512 + dchk * 8;
  }

  const f32x4 Z4 = {0.f, 0.f, 0.f, 0.f};
  f32x4 acc[4][4];
#pragma unroll
  for (int a = 0; a < 4; ++a)
#pragma unroll
    for (int c = 0; c < 4; ++c) acc[a][c] = Z4;

  // prologue: stage it=0 into buf 0
#pragma unroll
  for (int i = 0; i < 4; ++i) {
    int g = wv * 4 + i;
    ASYNC16(asrc[i], &As[0][g * 512]);
    ASYNC16(bsrc[i], &Bs[0][g * 512]);
  }
  __syncthreads();

  for (int it = 0; it < 8; ++it) {
    int buf = it & 1;
    if (it < 7) {
      int k1 = (it + 1) << 6;
#pragma unroll
      for (int i = 0; i < 4; ++i) {
        int g = wv * 4 + i;
        ASYNC16(asrc[i] + k1, &As[buf ^ 1][g * 512]);
        ASYNC16(bsrc[i] + k1, &Bs[buf ^ 1][g * 512]);
      }
    }
#pragma unroll
    for (int kk = 0; kk < 2; ++kk) {
      s16x8 af[4], bfr[4];
#pragma unroll
      for (int rb = 0; rb < 4; ++rb) {
        int row = wr + rb * 16 + l16;
        int c   = kk * 4 + quad;
        af[rb] = *(const s16x8*)(&As[buf][row * 64 + ((c ^ (row & 7)) * 8)]);
      }
#pragma unroll
      for (int cb = 0; cb < 4; ++cb) {
        int row = wc + cb * 16 + l16;
        int c   = kk * 4 + quad;
        bfr[cb] = *(const s16x8*)(&Bs[buf][row * 64 + ((c ^ (row & 7)) * 8)]);
      }
      if (mat < 2) {
#pragma unroll
        for (int rb = 0; rb < 4; ++rb)
#pragma unroll
          for (int cb = 0; cb < 4; ++cb)
            acc[rb][cb] = __builtin_amdgcn_mfma_f32_16x16x32_bf16(bfr[cb], af[rb], acc[rb][cb], 0, 0, 0);
      } else {
#pragma unroll
        for (int rb = 0; rb < 4; ++rb)
#pragma unroll
          for (int cb = 0; cb < 4; ++cb)
            acc[rb][cb] = __builtin_amdgcn_mfma_f32_16x16x32_bf16(af[rb], bfr[cb], acc[rb][cb], 0, 0, 0);
      }
    }
    __syncthreads();
  }

  if (mat < 2) {
    // acc[rb][cb] = C^T block: m = m0+wr+rb*16+l16 ; e = n0+wc+cb*16+quad*4+r
    short* D = (mat == 0) ? Qg : Kg;
#pragma unroll
    for (int cb = 0; cb < 4; ++cb) {
      f32x4 bv4 = *(const f32x4*)(bias + n0 + wc + cb * 16 + quad * 4);
#pragma unroll
      for (int rb = 0; rb < 4; ++rb) {
        u16x4 h;
#pragma unroll
        for (int r = 0; r < 4; ++r) h[r] = f2bf(acc[rb][cb][r] + bv4[r]);
        int m = m0 + wr + rb * 16 + l16;
        int e = n0 + wc + cb * 16 + quad * 4;
        *(u16x4*)(D + (size_t)m * 512 + e) = h;
      }
    }
  } else {
    // V: tiled transpose layout [bb][e>>4][s>>5][e&15][s&31], 1KB tiles
    float bsv[4];
#pragma unroll
    for (int cb = 0; cb < 4; ++cb) bsv[cb] = bias[n0 + wc + cb * 16 + l16];
#pragma unroll
    for (int rb = 0; rb < 4; ++rb)
#pragma unroll
      for (int cb = 0; cb < 4; ++cb) {
        u16x4 h;
#pragma unroll
        for (int r = 0; r < 4; ++r) h[r] = f2bf(acc[rb][cb][r] + bsv[cb]);
        int m  = m0 + wr + rb * 16 + quad * 4;
        int bb = m >> 11, sl = m & 2047;
        int e  = n0 + wc + cb * 16 + l16;
        size_t idx = ((((size_t)bb * 32 + (e >> 4)) * 64 + (sl >> 5)) * 16 +
                      (e & 15)) * 32 + (sl & 31);
        *(u16x4*)(VTg + idx) = h;
      }
  }
}

// ---------------- kernel 2: flash attention v7 (2 independent blocks/CU) ----------------
// 512 blocks (b=blk&7 -> XCD), 32 Q-rows/block, 4 waves, 2 blocks/CU (~70KB LDS).
// QK wave (a=wv&1: 16-row group, h=wv>>1: 16-key half); PV wave: e-slice wv*128.
// Per-iter: issue D(kt+1)x8 -> Kt[buf^1]; issue V(kt)x8 -> regs; QK(kt) from Kt[buf];
//   softmax -> Pl[buf]; asm "s_waitcnt vmcnt(8) lgkmcnt(0); s_barrier" (retires the
//   8 D ops exactly, keeps the 8 V ops in flight); PV(kt).
// Ledger: Kt RAW: D(kt) retired at barrier(kt-1) (8 oldest of 16). Kt WAR: D(kt+1)
//   issued post-barrier(kt-1); last Kt[buf^1] readers QK(kt-1) pre-barrier(kt-1).
//   V RAW: compiler-inserted vmcnt before vf use in PV. P RAW: lgkm(0)+barrier.
//   P WAR: Pl dbuf; barrier(kt+1) separates PV(kt) from SM(kt+2).
__global__ __launch_bounds__(256, 2) void attn_kernel(
    const short* __restrict__ Qg, const short* __restrict__ Kg,
    const short* __restrict__ VTg, float* __restrict__ out) {
  __shared__ __align__(16) short Kt[2][32 * 512];   // 64 KB double buffer
  __shared__ __align__(16) short Pl[2][32 * 40];    // 5 KB double buffer
  __shared__ float l_l[32];
  const float SCL2 = 0.06375871855f;  // log2(e)/sqrt(512)

  int b = blockIdx.x & 7, qt = blockIdx.x >> 3;   // qt 0..63
  int s0 = qt << 5;                                // 32 rows/block
  int tid = threadIdx.x, lane = tid & 63, wv = tid >> 6;  // wv 0..3
  int l16 = lane & 15, quad = lane >> 4;
  int a = wv & 1, h = wv >> 1;
  int e0 = wv << 7;                                // 128-wide e slice

  const short* Kb = Kg  + (size_t)b * S_LEN * 512;
  const short* Vb = VTg + (size_t)b * 1048576;     // [32 et][64 st][16][32]

  // K DMA per-lane source addresses (8 rows of 1KB per wave, swizzled source)
  const short* kdma[8];
#pragma unroll
  for (int i = 0; i < 8; ++i) {
    int r = wv * 8 + i;                            // r&7 == i
    kdma[i] = Kb + (size_t)r * 512 + ((lane ^ i) * 8);
  }
  // V fragment base: tile (et = wv*8+cb, st = kt); 1KB coalesced per load
  const short* vbase = Vb + (size_t)wv * 262144 + l16 * 32 + quad * 8;

  // ---- prologue: stage K tile 0 into Kt[0]; load Q frags ----
#pragma unroll
  for (int i = 0; i < 8; ++i)
    ASYNC16(kdma[i], &Kt[0][(wv * 8 + i) * 512]);

  const short* qrow = Qg + ((size_t)b * S_LEN + s0 + a * 16 + l16) * 512 + quad * 8;
  s16x8 qf[16];
#pragma unroll
  for (int kk = 0; kk < 16; ++kk) qf[kk] = *(const s16x8*)(qrow + kk * 32);

  const f32x4 Z4 = {0.f, 0.f, 0.f, 0.f};
  f32x4 acc[2][8];
#pragma unroll
  for (int g = 0; g < 2; ++g)
#pragma unroll
    for (int cb = 0; cb < 8; ++cb) acc[g][cb] = Z4;
  f32x4 lsum = Z4;

  __syncthreads();   // prologue full drain (one-time): K0 + Q landed

  for (int kt = 0; kt < 64; ++kt) {
    int buf = kt & 1;

    // ---- issue K-DMA(kt+1) -> Kt[buf^1] (full iter to land; wraps at tail) ----
    {
      size_t adv = (size_t)((kt + 1) & 63) * 16384;
#pragma unroll
      for (int i = 0; i < 8; ++i)
        ASYNC16(kdma[i] + adv, &Kt[buf ^ 1][(wv * 8 + i) * 512]);
    }
    __builtin_amdgcn_sched_barrier(0);   // D issued before V: vmcnt(8) retires D exactly

    // ---- issue V(kt) (global->reg, coalesced 1KB/wave) ----
    s16x8 vf[8];
#pragma unroll
    for (int cb = 0; cb < 8; ++cb)
      vf[cb] = *(const s16x8*)(vbase + (size_t)cb * 32768 + (size_t)kt * 512);
    __builtin_amdgcn_sched_barrier(0);

    // ---- QK: S[16 rows(a) x 16 keys(h)] from Kt[buf] ----
    f32x4 s_a = Z4, s_b = Z4;
    int krow = h * 16 + l16;
    const short* kb = &Kt[buf][krow * 512];
    int ksw = krow & 7;
    __builtin_amdgcn_s_setprio(1);
#pragma unroll
    for (int kk = 0; kk < 8; ++kk) {
      s16x8 kf0 = *(const s16x8*)(kb + (((2 * kk) * 4 + quad) ^ ksw) * 8);
      s_a = __builtin_amdgcn_mfma_f32_16x16x32_bf16(qf[2 * kk], kf0, s_a, 0, 0, 0);
      s16x8 kf1 = *(const s16x8*)(kb + (((2 * kk + 1) * 4 + quad) ^ ksw) * 8);
      s_b = __builtin_amdgcn_mfma_f32_16x16x32_bf16(qf[2 * kk + 1], kf1, s_b, 0, 0, 0);
    }
    __builtin_amdgcn_s_setprio(0);
    f32x4 sv = s_a + s_b;

    // ---- no-max softmax -> Pl[buf] ----
    short* Pc = Pl[buf];
#pragma unroll
    for (int r = 0; r < 4; ++r) {
      float p = exp2f(sv[r] * SCL2);
      lsum[r] += p;
      Pc[(a * 16 + quad * 4 + r) * 40 + h * 16 + l16] = (short)f2bf(p);
    }

    // ---- fused counted drain + barrier: retire D(kt+1), keep V(kt) in flight ----
    asm volatile("s_waitcnt vmcnt(8) lgkmcnt(0)\n\ts_barrier" ::: "memory");

    // ---- PV: O[32 x 128e] += P[32x32] @ V[32 x 128e] ----
    s16x8 pf[2];
#pragma unroll
    for (int g = 0; g < 2; ++g)
      pf[g] = *(const s16x8*)(Pc + (g * 16 + l16) * 40 + quad * 8);
    __builtin_amdgcn_s_setprio(1);
#pragma unroll
    for (int cb = 0; cb < 8; ++cb)
#pragma unroll
      for (int g = 0; g < 2; ++g)
        acc[g][cb] = __builtin_amdgcn_mfma_f32_16x16x32_bf16(pf[g], vf[cb], acc[g][cb], 0, 0, 0);
    __builtin_amdgcn_s_setprio(0);
  }

  // ---- epilogue: combine row sums (h halves), divide, store fp32 ----
#pragma unroll
  for (int r = 0; r < 4; ++r) {
    float v = lsum[r];
    v += __shfl_xor(v, 1);
    v += __shfl_xor(v, 2);
    v += __shfl_xor(v, 4);
    v += __shfl_xor(v, 8);
    lsum[r] = v;                    // sum over this wave's 16-key half
  }
  if (h == 0 && l16 == 0) {
#pragma unroll
    for (int r = 0; r < 4; ++r) l_l[a * 16 + quad * 4 + r] = lsum[r];
  }
  __syncthreads();
  if (h == 1 && l16 == 0) {
#pragma unroll
    for (int r = 0; r < 4; ++r) l_l[a * 16 + quad * 4 + r] += lsum[r];
  }
  __syncthreads();

#pragma unroll
  for (int g = 0; g < 2; ++g) {
    f32x4 lv = *(const f32x4*)(l_l + g * 16 + quad * 4);
    f32x4 li;
#pragma unroll
    for (int r = 0; r < 4; ++r) li[r] = 1.0f / lv[r];
#pragma unroll
    for (int cb = 0; cb < 8; ++cb)
#pragma unroll
      for (int r = 0; r < 4; ++r)
        out[((size_t)b * S_LEN + s0 + g * 16 + quad * 4 + r) * 512 + e0 + cb * 16 + l16] =
            acc[g][cb][r] * li[r];
  }
}

// ---------------- host launch ----------------
extern "C" void kernel_launch(void* const* d_in, const int* in_sizes, int n_in,
                              void* d_out, int out_size, void* d_ws, size_t ws_size,
                              hipStream_t stream) {
  const float* x  = (const float*)d_in[0];
  const float* Wq = (const float*)d_in[1];
  const float* bq = (const float*)d_in[2];
  const float* Wk = (const float*)d_in[3];
  const float* bk = (const float*)d_in[4];
  const float* Wv = (const float*)d_in[5];
  const float* bv = (const float*)d_in[6];

  short* Wt  = (short*)d_ws;
  short* xb  = (short*)((char*)d_ws + 1572864);
  short* Qg  = xb + (size_t)8388608;
  short* Kg  = Qg + (size_t)8388608;
  short* VTg = Kg + (size_t)8388608;

  conv_kernel<<<4288, 256, 0, stream>>>(x, xb, Wq, Wk, Wv, Wt);
  qkv_gemm<<<1536, 256, 0, stream>>>(xb, Wt, bq, bk, bv, Qg, Kg, VTg);
  attn_kernel<<<512, 256, 0, stream>>>(Qg, Kg, VTg, (float*)d_out);
}

// Round 8
// 222.365 us; speedup vs baseline: 1.1916x; 1.1916x over previous
//
#include <hip/hip_runtime.h>
#include <stdint.h>

// Self-attention, B=8 S=2048 D=E=512, fp32 in/out, bf16 MFMA internally.
//   xconv/wconv/qkv: R6 exact (residual measured 117 µs there).
//   attn v8: PRODUCER/CONSUMER wave specialization, 256 blocks x 8 waves.
//     QK waves (wv 0-3): 32 Q-rows x 16 keys each (a=wv&1 row-half, h=wv>>1
//       key-half); kf read ONCE, used for 2 row-groups -> QK LDS reads HALVED.
//     PV waves (wv 4-7): e-slice 128 each; V global->reg double-buffered
//       (vfA/vfB); run PV(kt-1) while QK computes S(kt).
//     Disjoint branches -> register lifetimes don't union (QK ~170, PV ~240).
//     Kt triple-buffered counted-vmcnt DMA (v6 ledger); Pl double-buffered;
//     ONE barrier/iter, counts matched across branches (64 + 2 epilogue).

using f32x4 = __attribute__((ext_vector_type(4))) float;
using s16x8 = __attribute__((ext_vector_type(8))) short;
using u16x4 = __attribute__((ext_vector_type(4))) unsigned short;

#define S_LEN 2048
#define EMB   512

#define ASYNC16(g, l)                                                     \
  __builtin_amdgcn_global_load_lds(                                       \
      (const __attribute__((address_space(1))) void*)(g),                 \
      (__attribute__((address_space(3))) void*)(l), 16, 0, 0)

__device__ __forceinline__ unsigned short f2bf(float f) {
  union { float f; unsigned u; } v; v.f = f;
  unsigned r = v.u + 0x7fffu + ((v.u >> 16) & 1u);   // RNE
  return (unsigned short)(r >> 16);
}

// ---------------- kernel 0: x fp32 -> bf16 ----------------
__global__ __launch_bounds__(256) void xconv_kernel(
    const float* __restrict__ x, short* __restrict__ xb) {
  int i = (blockIdx.x * 256 + threadIdx.x) * 8;
  f32x4 a = *(const f32x4*)(x + i);
  f32x4 b = *(const f32x4*)(x + i + 4);
  s16x8 h;
  h[0] = (short)f2bf(a[0]); h[1] = (short)f2bf(a[1]);
  h[2] = (short)f2bf(a[2]); h[3] = (short)f2bf(a[3]);
  h[4] = (short)f2bf(b[0]); h[5] = (short)f2bf(b[1]);
  h[6] = (short)f2bf(b[2]); h[7] = (short)f2bf(b[3]);
  *(s16x8*)(xb + i) = h;
}

// ---------------- kernel 1: weight transpose (LDS-tiled, coalesced) ----------------
__global__ __launch_bounds__(256) void wconv_kernel(
    const float* __restrict__ Wq, const float* __restrict__ Wk,
    const float* __restrict__ Wv, short* __restrict__ Wt) {
  __shared__ float T[64][65];
  int bid = blockIdx.x;
  int mat = bid >> 6;
  int t   = bid & 63;
  int k0  = (t & 7) << 6, n0 = (t >> 3) << 6;
  const float* W = (mat == 0) ? Wq : (mat == 1) ? Wk : Wv;
  int tid = threadIdx.x;
  int rr = tid >> 4, cc = tid & 15;
#pragma unroll
  for (int p = 0; p < 4; ++p) {
    int row = p * 16 + rr;
    f32x4 v = *(const f32x4*)(W + (size_t)(k0 + row) * 512 + n0 + cc * 4);
#pragma unroll
    for (int j = 0; j < 4; ++j) T[row][cc * 4 + j] = v[j];
  }
  __syncthreads();
  short* D = Wt + (size_t)mat * 262144;
#pragma unroll
  for (int p = 0; p < 4; ++p) {
    int nrow = p * 16 + rr;
    u16x4 h;
#pragma unroll
    for (int j = 0; j < 4; ++j) h[j] = f2bf(T[cc * 4 + j][nrow]);
    *(u16x4*)(D + (size_t)(n0 + nrow) * 512 + k0 + cc * 4) = h;
  }
}

// ---------------- kernel 2: QKV projection GEMM (R6 pipelined) ----------------
__global__ __launch_bounds__(256) void qkv_gemm(
    const short* __restrict__ xb, const short* __restrict__ Wt,
    const float* __restrict__ bq, const float* __restrict__ bk,
    const float* __restrict__ bv,
    short* __restrict__ Qg, short* __restrict__ Kg, short* __restrict__ VTg) {
  __shared__ __align__(16) short As[2][128 * 64];
  __shared__ __align__(16) short Bs[2][128 * 64];
  int gid = blockIdx.x;
  int mat = gid >> 9;
  int rem = gid & 511;
  int mt  = rem & 127, nt = rem >> 7;
  int m0  = mt << 7,   n0 = nt << 7;
  const short* W    = Wt + (size_t)mat * 262144;
  const float* bias = (mat == 0) ? bq : (mat == 1) ? bk : bv;

  int tid = threadIdx.x, lane = tid & 63, wv = tid >> 6;
  int l16 = lane & 15, quad = lane >> 4;
  int wr = (wv & 1) << 6, wc = (wv >> 1) << 6;
  int drow = lane >> 3;
  int dchk = (lane & 7) ^ drow;

  const short* asrc[4];
  const short* bsrc[4];
#pragma unroll
  for (int i = 0; i < 4; ++i) {
    int row = (wv * 4 + i) * 8 + drow;
    asrc[i] = xb + (size_t)(m0 + row) * 512 + dchk * 8;
    bsrc[i] = W  + (size_t)(n0 + row) * 512 + dchk * 8;
  }

  const f32x4 Z4 = {0.f, 0.f, 0.f, 0.f};
  f32x4 acc[4][4];
#pragma unroll
  for (int a = 0; a < 4; ++a)
#pragma unroll
    for (int c = 0; c < 4; ++c) acc[a][c] = Z4;

#pragma unroll
  for (int i = 0; i < 4; ++i) {
    int g = wv * 4 + i;
    ASYNC16(asrc[i], &As[0][g * 512]);
    ASYNC16(bsrc[i], &Bs[0][g * 512]);
  }
  __syncthreads();

  for (int it = 0; it < 8; ++it) {
    int buf = it & 1;
    if (it < 7) {
      int k1 = (it + 1) << 6;
#pragma unroll
      for (int i = 0; i < 4; ++i) {
        int g = wv * 4 + i;
        ASYNC16(asrc[i] + k1, &As[buf ^ 1][g * 512]);
        ASYNC16(bsrc[i] + k1, &Bs[buf ^ 1][g * 512]);
      }
    }
#pragma unroll
    for (int kk = 0; kk < 2; ++kk) {
      s16x8 af[4], bfr[4];
#pragma unroll
      for (int rb = 0; rb < 4; ++rb) {
        int row = wr + rb * 16 + l16;
        int c   = kk * 4 + quad;
        af[rb] = *(const s16x8*)(&As[buf][row * 64 + ((c ^ (row & 7)) * 8)]);
      }
#pragma unroll
      for (int cb = 0; cb < 4; ++cb) {
        int row = wc + cb * 16 + l16;
        int c   = kk * 4 + quad;
        bfr[cb] = *(const s16x8*)(&Bs[buf][row * 64 + ((c ^ (row & 7)) * 8)]);
      }
#pragma unroll
      for (int rb = 0; rb < 4; ++rb)
#pragma unroll
        for (int cb = 0; cb < 4; ++cb)
          acc[rb][cb] = __builtin_amdgcn_mfma_f32_16x16x32_bf16(af[rb], bfr[cb], acc[rb][cb], 0, 0, 0);
    }
    __syncthreads();
  }

  float bsv[4];
#pragma unroll
  for (int cb = 0; cb < 4; ++cb) bsv[cb] = bias[n0 + wc + cb * 16 + l16];

  if (mat < 2) {
    short* D = (mat == 0) ? Qg : Kg;
#pragma unroll
    for (int rb = 0; rb < 4; ++rb)
#pragma unroll
      for (int cb = 0; cb < 4; ++cb)
#pragma unroll
        for (int r = 0; r < 4; ++r) {
          int m = m0 + wr + rb * 16 + quad * 4 + r;
          D[(size_t)m * 512 + n0 + wc + cb * 16 + l16] =
              (short)f2bf(acc[rb][cb][r] + bsv[cb]);
        }
  } else {
#pragma unroll
    for (int rb = 0; rb < 4; ++rb)
#pragma unroll
      for (int cb = 0; cb < 4; ++cb) {
        u16x4 h;
#pragma unroll
        for (int r = 0; r < 4; ++r) h[r] = f2bf(acc[rb][cb][r] + bsv[cb]);
        int m  = m0 + wr + rb * 16 + quad * 4;
        int bb = m >> 11, sl = m & 2047;
        int e  = n0 + wc + cb * 16 + l16;
        size_t idx = ((((size_t)bb * 32 + (e >> 4)) * 64 + (sl >> 5)) * 16 +
                      (e & 15)) * 32 + (sl & 31);
        *(u16x4*)(VTg + idx) = h;
      }
  }
}

// ---------------- kernel 3: flash attention v8 (wave specialization) ----------------
// 256 blocks (b=blk&7 -> XCD), 64 Q-rows/block, 8 waves, 1 block/CU.
// Barrier schedule (both branches): 64 loop barriers + 2 epilogue barriers.
// vmcnt ledger:
//   QK wave: only D ops (4/iter). At bar(k): outstanding D(k+1)4 + D(k+2)4 ->
//     asm vmcnt(4) retires D(k+1) exactly (2-iter landing window).
//   PV wave: issue D(k+2)4 then V(k)4..; compiler-auto vmcnt before vf use
//     retires V(k-1) AND the older D(k+1) -> D visible before bar(k) block-wide.
// P handoff: QK writes P(k)->Pl[k&1] pre-bar(k); PV reads it post-bar(k) in
//   iter k+1. WAR: Pl[k&1] rewritten at k+2 post-bar(k+1); read pre-bar(k+1).
__global__ __launch_bounds__(512, 2) void attn_kernel(
    const short* __restrict__ Qg, const short* __restrict__ Kg,
    const short* __restrict__ VTg, float* __restrict__ out) {
  __shared__ __align__(16) short Kt[3][32 * 512];   // 96 KB triple buffer
  __shared__ __align__(16) short Pl[2][64 * 40];    // 10 KB double buffer
  __shared__ float l_l[64];
  const float SCL2 = 0.06375871855f;  // log2(e)/sqrt(512)

  int b = blockIdx.x & 7, qt = blockIdx.x >> 3;   // qt 0..31
  int s0 = qt << 6;                                // 64 rows/block
  int tid = threadIdx.x, lane = tid & 63, wv = tid >> 6;  // wv 0..7
  int l16 = lane & 15, quad = lane >> 4;

  const short* Kb = Kg  + (size_t)b * S_LEN * 512;
  const short* Vb = VTg + (size_t)b * 1048576;     // [32 et][64 st][16][32]

  // K DMA per-lane source addresses (4 rows of 1KB per wave, swizzled source)
  const short* kdma[4];
#pragma unroll
  for (int i = 0; i < 4; ++i) {
    int r = wv * 4 + i;
    kdma[i] = Kb + (size_t)r * 512 + ((lane ^ (r & 7)) * 8);
  }

  // ---- prologue: stage K tiles 0,1 (all waves) ----
#pragma unroll
  for (int i = 0; i < 4; ++i)
    ASYNC16(kdma[i], &Kt[0][(wv * 4 + i) * 512]);
#pragma unroll
  for (int i = 0; i < 4; ++i)
    ASYNC16(kdma[i] + 16384, &Kt[1][(wv * 4 + i) * 512]);

  if (wv < 4) {
    // ================= QK producer branch =================
    int a = wv & 1, h = wv >> 1;                   // 32-row half, 16-key half
    const short* qrowA = Qg + ((size_t)b * S_LEN + s0 + a * 32 + l16) * 512 + quad * 8;
    const short* qrowB = qrowA + (size_t)16 * 512;
    s16x8 qfA[16], qfB[16];
#pragma unroll
    for (int c = 0; c < 16; ++c) {
      qfA[c] = *(const s16x8*)(qrowA + c * 32);
      qfB[c] = *(const s16x8*)(qrowB + c * 32);
    }
    const f32x4 Z4 = {0.f, 0.f, 0.f, 0.f};
    f32x4 lsumA = Z4, lsumB = Z4;

    __syncthreads();   // prologue drain (K0,K1 + qf)  [barrier #0]

    for (int kt = 0; kt < 64; ++kt) {
      int rbuf = kt % 3, wbuf = (kt + 2) % 3;
      // issue D(kt+2)
      {
        size_t adv = (size_t)((kt + 2) & 63) * 16384;
#pragma unroll
        for (int i = 0; i < 4; ++i)
          ASYNC16(kdma[i] + adv, &Kt[wbuf][(wv * 4 + i) * 512]);
      }
      __builtin_amdgcn_sched_barrier(0);

      // QK: S[32 rows(a) x 16 keys(h)]; each kf used by both row-groups
      f32x4 sA = Z4, sB = Z4;
      int krow = h * 16 + l16;
      const short* kb = &Kt[rbuf][krow * 512];
      int ksw = krow & 7;
      __builtin_amdgcn_s_setprio(1);
#pragma unroll
      for (int c = 0; c < 16; ++c) {
        s16x8 kf = *(const s16x8*)(kb + (((c * 4 + quad) ^ ksw) * 8));
        sA = __builtin_amdgcn_mfma_f32_16x16x32_bf16(qfA[c], kf, sA, 0, 0, 0);
        sB = __builtin_amdgcn_mfma_f32_16x16x32_bf16(qfB[c], kf, sB, 0, 0, 0);
      }
      __builtin_amdgcn_s_setprio(0);

      // softmax -> Pl[kt&1]
      short* Pc = Pl[kt & 1];
#pragma unroll
      for (int r = 0; r < 4; ++r) {
        float pA = exp2f(sA[r] * SCL2);
        lsumA[r] += pA;
        Pc[(a * 32 + quad * 4 + r) * 40 + h * 16 + l16] = (short)f2bf(pA);
        float pB = exp2f(sB[r] * SCL2);
        lsumB[r] += pB;
        Pc[(a * 32 + 16 + quad * 4 + r) * 40 + h * 16 + l16] = (short)f2bf(pB);
      }

      // counted drain: retire D(kt+1), keep D(kt+2) in flight
      asm volatile("s_waitcnt vmcnt(4) lgkmcnt(0)\n\ts_barrier" ::: "memory");
      __builtin_amdgcn_sched_barrier(0);
    }

    // ---- QK epilogue: reduce row-sums over 16 keys, combine h halves ----
#pragma unroll
    for (int r = 0; r < 4; ++r) {
      float vA = lsumA[r];
      vA += __shfl_xor(vA, 1); vA += __shfl_xor(vA, 2);
      vA += __shfl_xor(vA, 4); vA += __shfl_xor(vA, 8);
      lsumA[r] = vA;
      float vB = lsumB[r];
      vB += __shfl_xor(vB, 1); vB += __shfl_xor(vB, 2);
      vB += __shfl_xor(vB, 4); vB += __shfl_xor(vB, 8);
      lsumB[r] = vB;
    }
    if (h == 0 && l16 == 0) {
#pragma unroll
      for (int r = 0; r < 4; ++r) {
        l_l[a * 32 + quad * 4 + r]      = lsumA[r];
        l_l[a * 32 + 16 + quad * 4 + r] = lsumB[r];
      }
    }
    __syncthreads();   // epilogue barrier #1
    if (h == 1 && l16 == 0) {
#pragma unroll
      for (int r = 0; r < 4; ++r) {
        l_l[a * 32 + quad * 4 + r]      += lsumA[r];
        l_l[a * 32 + 16 + quad * 4 + r] += lsumB[r];
      }
    }
    __syncthreads();   // epilogue barrier #2
  } else {
    // ================= PV consumer branch =================
    int pw = wv - 4;                               // 0..3
    int e0 = pw << 7;                              // 128-wide e slice
    const short* vbase = Vb + (size_t)pw * 262144 + l16 * 32 + quad * 8;

    const f32x4 Z4 = {0.f, 0.f, 0.f, 0.f};
    f32x4 acc[4][8];
#pragma unroll
    for (int g = 0; g < 4; ++g)
#pragma unroll
      for (int cb = 0; cb < 8; ++cb) acc[g][cb] = Z4;
    s16x8 vfA[8], vfB[8];

    __syncthreads();   // prologue drain  [barrier #0]

    for (int kt = 0; kt < 64; kt += 2) {
      // ---- half A (even kt): load V(kt)->vfA; PV(kt-1) with vfB ----
      {
        size_t adv = (size_t)((kt + 2) & 63) * 16384;
        int wbuf = (kt + 2) % 3;
#pragma unroll
        for (int i = 0; i < 4; ++i)
          ASYNC16(kdma[i] + adv, &Kt[wbuf][(wv * 4 + i) * 512]);
      }
#pragma unroll
      for (int cb = 0; cb < 8; ++cb)
        vfA[cb] = *(const s16x8*)(vbase + (size_t)cb * 32768 + (size_t)kt * 512);
      if (kt) {
        s16x8 pf[4];
#pragma unroll
        for (int g = 0; g < 4; ++g)
          pf[g] = *(const s16x8*)(&Pl[1][(g * 16 + l16) * 40 + quad * 8]);
        __builtin_amdgcn_s_setprio(1);
#pragma unroll
        for (int cb = 0; cb < 8; ++cb)
#pragma unroll
          for (int g = 0; g < 4; ++g)
            acc[g][cb] = __builtin_amdgcn_mfma_f32_16x16x32_bf16(pf[g], vfB[cb], acc[g][cb], 0, 0, 0);
        __builtin_amdgcn_s_setprio(0);
      }
      asm volatile("s_waitcnt lgkmcnt(0)\n\ts_barrier" ::: "memory");
      __builtin_amdgcn_sched_barrier(0);

      // ---- half B (kt+1): load V(kt+1)->vfB; PV(kt) with vfA ----
      {
        size_t adv = (size_t)((kt + 3) & 63) * 16384;
        int wbuf = (kt + 3) % 3;
#pragma unroll
        for (int i = 0; i < 4; ++i)
          ASYNC16(kdma[i] + adv, &Kt[wbuf][(wv * 4 + i) * 512]);
      }
#pragma unroll
      for (int cb = 0; cb < 8; ++cb)
        vfB[cb] = *(const s16x8*)(vbase + (size_t)cb * 32768 + (size_t)(kt + 1) * 512);
      {
        s16x8 pf[4];
#pragma unroll
        for (int g = 0; g < 4; ++g)
          pf[g] = *(const s16x8*)(&Pl[0][(g * 16 + l16) * 40 + quad * 8]);
        __builtin_amdgcn_s_setprio(1);
#pragma unroll
        for (int cb = 0; cb < 8; ++cb)
#pragma unroll
          for (int g = 0; g < 4; ++g)
            acc[g][cb] = __builtin_amdgcn_mfma_f32_16x16x32_bf16(pf[g], vfA[cb], acc[g][cb], 0, 0, 0);
        __builtin_amdgcn_s_setprio(0);
      }
      asm volatile("s_waitcnt lgkmcnt(0)\n\ts_barrier" ::: "memory");
      __builtin_amdgcn_sched_barrier(0);
    }

    // ---- PV epilogue: final PV(63) with vfB (loaded in last half-B) ----
    asm volatile("s_waitcnt vmcnt(0)" ::: "memory");
    __builtin_amdgcn_sched_barrier(0);
    {
      s16x8 pf[4];
#pragma unroll
      for (int g = 0; g < 4; ++g)
        pf[g] = *(const s16x8*)(&Pl[1][(g * 16 + l16) * 40 + quad * 8]);
#pragma unroll
      for (int cb = 0; cb < 8; ++cb)
#pragma unroll
        for (int g = 0; g < 4; ++g)
          acc[g][cb] = __builtin_amdgcn_mfma_f32_16x16x32_bf16(pf[g], vfB[cb], acc[g][cb], 0, 0, 0);
    }
    __syncthreads();   // epilogue barrier #1 (matches QK's l_l h0 barrier)
    __syncthreads();   // epilogue barrier #2 (l_l complete after this)

    // ---- divide by row-sums, store fp32 ----
#pragma unroll
    for (int g = 0; g < 4; ++g) {
      f32x4 lv = *(const f32x4*)(l_l + g * 16 + quad * 4);
      f32x4 li;
#pragma unroll
      for (int r = 0; r < 4; ++r) li[r] = 1.0f / lv[r];
#pragma unroll
      for (int cb = 0; cb < 8; ++cb)
#pragma unroll
        for (int r = 0; r < 4; ++r)
          out[((size_t)b * S_LEN + s0 + g * 16 + quad * 4 + r) * 512 + e0 + cb * 16 + l16] =
              acc[g][cb][r] * li[r];
    }
  }
}

// ---------------- host launch ----------------
extern "C" void kernel_launch(void* const* d_in, const int* in_sizes, int n_in,
                              void* d_out, int out_size, void* d_ws, size_t ws_size,
                              hipStream_t stream) {
  const float* x  = (const float*)d_in[0];
  const float* Wq = (const float*)d_in[1];
  const float* bq = (const float*)d_in[2];
  const float* Wk = (const float*)d_in[3];
  const float* bk = (const float*)d_in[4];
  const float* Wv = (const float*)d_in[5];
  const float* bv = (const float*)d_in[6];

  short* Wt  = (short*)d_ws;
  short* xb  = (short*)((char*)d_ws + 1572864);
  short* Qg  = xb + (size_t)8388608;
  short* Kg  = Qg + (size_t)8388608;
  short* VTg = Kg + (size_t)8388608;

  xconv_kernel<<<4096, 256, 0, stream>>>(x, xb);
  wconv_kernel<<<192, 256, 0, stream>>>(Wq, Wk, Wv, Wt);
  qkv_gemm<<<1536, 256, 0, stream>>>(xb, Wt, bq, bk, bv, Qg, Kg, VTg);
  attn_kernel<<<256, 512, 0, stream>>>(Qg, Kg, VTg, (float*)d_out);
}

// Round 9
// 219.447 us; speedup vs baseline: 1.2075x; 1.0133x over previous
//
#include <hip/hip_runtime.h>
#include <stdint.h>

// Self-attention, B=8 S=2048 D=E=512, fp32 in/out, bf16 MFMA internally.
//   xconv/wconv: unchanged (R6).
//   qkv v3: R6 pipelined structure + XCD-PINNED m-partitioning:
//     gid -> xcd = gid&7 owns m-tiles [xcd*16, xcd*16+16)  (xb slice 2.1MB + W
//     1.5MB fits the XCD's 4MB L2 -> all 12 A-panel re-reads become L2 hits;
//     A-sharers (mat,nt) adjacent in slot order). Also batch = mt>>4 = xcd,
//     matching attn's b=blk&7 pinning (Q/K/V produced where consumed).
//   attn v8: unchanged (measured 102.7 µs): producer/consumer wave split,
//     QK waves 32rows x 16keys (kf dedup), PV waves e-slice 128, Kt triple-
//     buffered counted-vmcnt DMA, Pl double-buffered, 1 barrier/iter.

using f32x4 = __attribute__((ext_vector_type(4))) float;
using s16x8 = __attribute__((ext_vector_type(8))) short;
using u16x4 = __attribute__((ext_vector_type(4))) unsigned short;

#define S_LEN 2048
#define EMB   512

#define ASYNC16(g, l)                                                     \
  __builtin_amdgcn_global_load_lds(                                       \
      (const __attribute__((address_space(1))) void*)(g),                 \
      (__attribute__((address_space(3))) void*)(l), 16, 0, 0)

__device__ __forceinline__ unsigned short f2bf(float f) {
  union { float f; unsigned u; } v; v.f = f;
  unsigned r = v.u + 0x7fffu + ((v.u >> 16) & 1u);   // RNE
  return (unsigned short)(r >> 16);
}

// ---------------- kernel 0: x fp32 -> bf16 ----------------
__global__ __launch_bounds__(256) void xconv_kernel(
    const float* __restrict__ x, short* __restrict__ xb) {
  int i = (blockIdx.x * 256 + threadIdx.x) * 8;
  f32x4 a = *(const f32x4*)(x + i);
  f32x4 b = *(const f32x4*)(x + i + 4);
  s16x8 h;
  h[0] = (short)f2bf(a[0]); h[1] = (short)f2bf(a[1]);
  h[2] = (short)f2bf(a[2]); h[3] = (short)f2bf(a[3]);
  h[4] = (short)f2bf(b[0]); h[5] = (short)f2bf(b[1]);
  h[6] = (short)f2bf(b[2]); h[7] = (short)f2bf(b[3]);
  *(s16x8*)(xb + i) = h;
}

// ---------------- kernel 1: weight transpose (LDS-tiled, coalesced) ----------------
__global__ __launch_bounds__(256) void wconv_kernel(
    const float* __restrict__ Wq, const float* __restrict__ Wk,
    const float* __restrict__ Wv, short* __restrict__ Wt) {
  __shared__ float T[64][65];
  int bid = blockIdx.x;
  int mat = bid >> 6;
  int t   = bid & 63;
  int k0  = (t & 7) << 6, n0 = (t >> 3) << 6;
  const float* W = (mat == 0) ? Wq : (mat == 1) ? Wk : Wv;
  int tid = threadIdx.x;
  int rr = tid >> 4, cc = tid & 15;
#pragma unroll
  for (int p = 0; p < 4; ++p) {
    int row = p * 16 + rr;
    f32x4 v = *(const f32x4*)(W + (size_t)(k0 + row) * 512 + n0 + cc * 4);
#pragma unroll
    for (int j = 0; j < 4; ++j) T[row][cc * 4 + j] = v[j];
  }
  __syncthreads();
  short* D = Wt + (size_t)mat * 262144;
#pragma unroll
  for (int p = 0; p < 4; ++p) {
    int nrow = p * 16 + rr;
    u16x4 h;
#pragma unroll
    for (int j = 0; j < 4; ++j) h[j] = f2bf(T[cc * 4 + j][nrow]);
    *(u16x4*)(D + (size_t)(n0 + nrow) * 512 + k0 + cc * 4) = h;
  }
}

// ---------------- kernel 2: QKV projection GEMM (pipelined + XCD-pinned m) ----------------
__global__ __launch_bounds__(256) void qkv_gemm(
    const short* __restrict__ xb, const short* __restrict__ Wt,
    const float* __restrict__ bq, const float* __restrict__ bk,
    const float* __restrict__ bv,
    short* __restrict__ Qg, short* __restrict__ Kg, short* __restrict__ VTg) {
  __shared__ __align__(16) short As[2][128 * 64];
  __shared__ __align__(16) short Bs[2][128 * 64];
  // XCD-pinned decode: xcd = gid&7 owns m-tiles [xcd*16, xcd*16+16).
  // slot s = gid>>3 in [0,192): mt_local = s/12 (slow), j = s%12 -> (mat, nt)
  // fast so the 12 sharers of an A-panel are dispatched adjacently.
  int gid = blockIdx.x;
  int xcd = gid & 7;
  int s   = gid >> 3;
  int mt_l = s / 12;
  int j    = s - mt_l * 12;
  int mat  = j >> 2;
  int nt   = j & 3;
  int mt   = xcd * 16 + mt_l;
  int m0   = mt << 7, n0 = nt << 7;
  const short* W    = Wt + (size_t)mat * 262144;
  const float* bias = (mat == 0) ? bq : (mat == 1) ? bk : bv;

  int tid = threadIdx.x, lane = tid & 63, wv = tid >> 6;
  int l16 = lane & 15, quad = lane >> 4;
  int wr = (wv & 1) << 6, wc = (wv >> 1) << 6;
  int drow = lane >> 3;
  int dchk = (lane & 7) ^ drow;

  const short* asrc[4];
  const short* bsrc[4];
#pragma unroll
  for (int i = 0; i < 4; ++i) {
    int row = (wv * 4 + i) * 8 + drow;
    asrc[i] = xb + (size_t)(m0 + row) * 512 + dchk * 8;
    bsrc[i] = W  + (size_t)(n0 + row) * 512 + dchk * 8;
  }

  const f32x4 Z4 = {0.f, 0.f, 0.f, 0.f};
  f32x4 acc[4][4];
#pragma unroll
  for (int a = 0; a < 4; ++a)
#pragma unroll
    for (int c = 0; c < 4; ++c) acc[a][c] = Z4;

#pragma unroll
  for (int i = 0; i < 4; ++i) {
    int g = wv * 4 + i;
    ASYNC16(asrc[i], &As[0][g * 512]);
    ASYNC16(bsrc[i], &Bs[0][g * 512]);
  }
  __syncthreads();

  for (int it = 0; it < 8; ++it) {
    int buf = it & 1;
    if (it < 7) {
      int k1 = (it + 1) << 6;
#pragma unroll
      for (int i = 0; i < 4; ++i) {
        int g = wv * 4 + i;
        ASYNC16(asrc[i] + k1, &As[buf ^ 1][g * 512]);
        ASYNC16(bsrc[i] + k1, &Bs[buf ^ 1][g * 512]);
      }
    }
#pragma unroll
    for (int kk = 0; kk < 2; ++kk) {
      s16x8 af[4], bfr[4];
#pragma unroll
      for (int rb = 0; rb < 4; ++rb) {
        int row = wr + rb * 16 + l16;
        int c   = kk * 4 + quad;
        af[rb] = *(const s16x8*)(&As[buf][row * 64 + ((c ^ (row & 7)) * 8)]);
      }
#pragma unroll
      for (int cb = 0; cb < 4; ++cb) {
        int row = wc + cb * 16 + l16;
        int c   = kk * 4 + quad;
        bfr[cb] = *(const s16x8*)(&Bs[buf][row * 64 + ((c ^ (row & 7)) * 8)]);
      }
#pragma unroll
      for (int rb = 0; rb < 4; ++rb)
#pragma unroll
        for (int cb = 0; cb < 4; ++cb)
          acc[rb][cb] = __builtin_amdgcn_mfma_f32_16x16x32_bf16(af[rb], bfr[cb], acc[rb][cb], 0, 0, 0);
    }
    __syncthreads();
  }

  float bsv[4];
#pragma unroll
  for (int cb = 0; cb < 4; ++cb) bsv[cb] = bias[n0 + wc + cb * 16 + l16];

  if (mat < 2) {
    short* D = (mat == 0) ? Qg : Kg;
#pragma unroll
    for (int rb = 0; rb < 4; ++rb)
#pragma unroll
      for (int cb = 0; cb < 4; ++cb)
#pragma unroll
        for (int r = 0; r < 4; ++r) {
          int m = m0 + wr + rb * 16 + quad * 4 + r;
          D[(size_t)m * 512 + n0 + wc + cb * 16 + l16] =
              (short)f2bf(acc[rb][cb][r] + bsv[cb]);
        }
  } else {
#pragma unroll
    for (int rb = 0; rb < 4; ++rb)
#pragma unroll
      for (int cb = 0; cb < 4; ++cb) {
        u16x4 h;
#pragma unroll
        for (int r = 0; r < 4; ++r) h[r] = f2bf(acc[rb][cb][r] + bsv[cb]);
        int m  = m0 + wr + rb * 16 + quad * 4;
        int bb = m >> 11, sl = m & 2047;
        int e  = n0 + wc + cb * 16 + l16;
        size_t idx = ((((size_t)bb * 32 + (e >> 4)) * 64 + (sl >> 5)) * 16 +
                      (e & 15)) * 32 + (sl & 31);
        *(u16x4*)(VTg + idx) = h;
      }
  }
}

// ---------------- kernel 3: flash attention v8 (wave specialization) ----------------
// UNCHANGED from round 8 (measured 102.7 µs, passed).
__global__ __launch_bounds__(512, 2) void attn_kernel(
    const short* __restrict__ Qg, const short* __restrict__ Kg,
    const short* __restrict__ VTg, float* __restrict__ out) {
  __shared__ __align__(16) short Kt[3][32 * 512];   // 96 KB triple buffer
  __shared__ __align__(16) short Pl[2][64 * 40];    // 10 KB double buffer
  __shared__ float l_l[64];
  const float SCL2 = 0.06375871855f;  // log2(e)/sqrt(512)

  int b = blockIdx.x & 7, qt = blockIdx.x >> 3;   // qt 0..31
  int s0 = qt << 6;                                // 64 rows/block
  int tid = threadIdx.x, lane = tid & 63, wv = tid >> 6;  // wv 0..7
  int l16 = lane & 15, quad = lane >> 4;

  const short* Kb = Kg  + (size_t)b * S_LEN * 512;
  const short* Vb = VTg + (size_t)b * 1048576;     // [32 et][64 st][16][32]

  const short* kdma[4];
#pragma unroll
  for (int i = 0; i < 4; ++i) {
    int r = wv * 4 + i;
    kdma[i] = Kb + (size_t)r * 512 + ((lane ^ (r & 7)) * 8);
  }

#pragma unroll
  for (int i = 0; i < 4; ++i)
    ASYNC16(kdma[i], &Kt[0][(wv * 4 + i) * 512]);
#pragma unroll
  for (int i = 0; i < 4; ++i)
    ASYNC16(kdma[i] + 16384, &Kt[1][(wv * 4 + i) * 512]);

  if (wv < 4) {
    // ================= QK producer branch =================
    int a = wv & 1, h = wv >> 1;
    const short* qrowA = Qg + ((size_t)b * S_LEN + s0 + a * 32 + l16) * 512 + quad * 8;
    const short* qrowB = qrowA + (size_t)16 * 512;
    s16x8 qfA[16], qfB[16];
#pragma unroll
    for (int c = 0; c < 16; ++c) {
      qfA[c] = *(const s16x8*)(qrowA + c * 32);
      qfB[c] = *(const s16x8*)(qrowB + c * 32);
    }
    const f32x4 Z4 = {0.f, 0.f, 0.f, 0.f};
    f32x4 lsumA = Z4, lsumB = Z4;

    __syncthreads();   // prologue drain  [barrier #0]

    for (int kt = 0; kt < 64; ++kt) {
      int rbuf = kt % 3, wbuf = (kt + 2) % 3;
      {
        size_t adv = (size_t)((kt + 2) & 63) * 16384;
#pragma unroll
        for (int i = 0; i < 4; ++i)
          ASYNC16(kdma[i] + adv, &Kt[wbuf][(wv * 4 + i) * 512]);
      }
      __builtin_amdgcn_sched_barrier(0);

      f32x4 sA = Z4, sB = Z4;
      int krow = h * 16 + l16;
      const short* kb = &Kt[rbuf][krow * 512];
      int ksw = krow & 7;
      __builtin_amdgcn_s_setprio(1);
#pragma unroll
      for (int c = 0; c < 16; ++c) {
        s16x8 kf = *(const s16x8*)(kb + (((c * 4 + quad) ^ ksw) * 8));
        sA = __builtin_amdgcn_mfma_f32_16x16x32_bf16(qfA[c], kf, sA, 0, 0, 0);
        sB = __builtin_amdgcn_mfma_f32_16x16x32_bf16(qfB[c], kf, sB, 0, 0, 0);
      }
      __builtin_amdgcn_s_setprio(0);

      short* Pc = Pl[kt & 1];
#pragma unroll
      for (int r = 0; r < 4; ++r) {
        float pA = exp2f(sA[r] * SCL2);
        lsumA[r] += pA;
        Pc[(a * 32 + quad * 4 + r) * 40 + h * 16 + l16] = (short)f2bf(pA);
        float pB = exp2f(sB[r] * SCL2);
        lsumB[r] += pB;
        Pc[(a * 32 + 16 + quad * 4 + r) * 40 + h * 16 + l16] = (short)f2bf(pB);
      }

      asm volatile("s_waitcnt vmcnt(4) lgkmcnt(0)\n\ts_barrier" ::: "memory");
      __builtin_amdgcn_sched_barrier(0);
    }

#pragma unroll
    for (int r = 0; r < 4; ++r) {
      float vA = lsumA[r];
      vA += __shfl_xor(vA, 1); vA += __shfl_xor(vA, 2);
      vA += __shfl_xor(vA, 4); vA += __shfl_xor(vA, 8);
      lsumA[r] = vA;
      float vB = lsumB[r];
      vB += __shfl_xor(vB, 1); vB += __shfl_xor(vB, 2);
      vB += __shfl_xor(vB, 4); vB += __shfl_xor(vB, 8);
      lsumB[r] = vB;
    }
    if (h == 0 && l16 == 0) {
#pragma unroll
      for (int r = 0; r < 4; ++r) {
        l_l[a * 32 + quad * 4 + r]      = lsumA[r];
        l_l[a * 32 + 16 + quad * 4 + r] = lsumB[r];
      }
    }
    __syncthreads();   // epilogue barrier #1
    if (h == 1 && l16 == 0) {
#pragma unroll
      for (int r = 0; r < 4; ++r) {
        l_l[a * 32 + quad * 4 + r]      += lsumA[r];
        l_l[a * 32 + 16 + quad * 4 + r] += lsumB[r];
      }
    }
    __syncthreads();   // epilogue barrier #2
  } else {
    // ================= PV consumer branch =================
    int pw = wv - 4;
    int e0 = pw << 7;
    const short* vbase = Vb + (size_t)pw * 262144 + l16 * 32 + quad * 8;

    const f32x4 Z4 = {0.f, 0.f, 0.f, 0.f};
    f32x4 acc[4][8];
#pragma unroll
    for (int g = 0; g < 4; ++g)
#pragma unroll
      for (int cb = 0; cb < 8; ++cb) acc[g][cb] = Z4;
    s16x8 vfA[8], vfB[8];

    __syncthreads();   // prologue drain  [barrier #0]

    for (int kt = 0; kt < 64; kt += 2) {
      {
        size_t adv = (size_t)((kt + 2) & 63) * 16384;
        int wbuf = (kt + 2) % 3;
#pragma unroll
        for (int i = 0; i < 4; ++i)
          ASYNC16(kdma[i] + adv, &Kt[wbuf][(wv * 4 + i) * 512]);
      }
#pragma unroll
      for (int cb = 0; cb < 8; ++cb)
        vfA[cb] = *(const s16x8*)(vbase + (size_t)cb * 32768 + (size_t)kt * 512);
      if (kt) {
        s16x8 pf[4];
#pragma unroll
        for (int g = 0; g < 4; ++g)
          pf[g] = *(const s16x8*)(&Pl[1][(g * 16 + l16) * 40 + quad * 8]);
        __builtin_amdgcn_s_setprio(1);
#pragma unroll
        for (int cb = 0; cb < 8; ++cb)
#pragma unroll
          for (int g = 0; g < 4; ++g)
            acc[g][cb] = __builtin_amdgcn_mfma_f32_16x16x32_bf16(pf[g], vfB[cb], acc[g][cb], 0, 0, 0);
        __builtin_amdgcn_s_setprio(0);
      }
      asm volatile("s_waitcnt lgkmcnt(0)\n\ts_barrier" ::: "memory");
      __builtin_amdgcn_sched_barrier(0);

      {
        size_t adv = (size_t)((kt + 3) & 63) * 16384;
        int wbuf = (kt + 3) % 3;
#pragma unroll
        for (int i = 0; i < 4; ++i)
          ASYNC16(kdma[i] + adv, &Kt[wbuf][(wv * 4 + i) * 512]);
      }
#pragma unroll
      for (int cb = 0; cb < 8; ++cb)
        vfB[cb] = *(const s16x8*)(vbase + (size_t)cb * 32768 + (size_t)(kt + 1) * 512);
      {
        s16x8 pf[4];
#pragma unroll
        for (int g = 0; g < 4; ++g)
          pf[g] = *(const s16x8*)(&Pl[0][(g * 16 + l16) * 40 + quad * 8]);
        __builtin_amdgcn_s_setprio(1);
#pragma unroll
        for (int cb = 0; cb < 8; ++cb)
#pragma unroll
          for (int g = 0; g < 4; ++g)
            acc[g][cb] = __builtin_amdgcn_mfma_f32_16x16x32_bf16(pf[g], vfA[cb], acc[g][cb], 0, 0, 0);
        __builtin_amdgcn_s_setprio(0);
      }
      asm volatile("s_waitcnt lgkmcnt(0)\n\ts_barrier" ::: "memory");
      __builtin_amdgcn_sched_barrier(0);
    }

    asm volatile("s_waitcnt vmcnt(0)" ::: "memory");
    __builtin_amdgcn_sched_barrier(0);
    {
      s16x8 pf[4];
#pragma unroll
      for (int g = 0; g < 4; ++g)
        pf[g] = *(const s16x8*)(&Pl[1][(g * 16 + l16) * 40 + quad * 8]);
#pragma unroll
      for (int cb = 0; cb < 8; ++cb)
#pragma unroll
        for (int g = 0; g < 4; ++g)
          acc[g][cb] = __builtin_amdgcn_mfma_f32_16x16x32_bf16(pf[g], vfB[cb], acc[g][cb], 0, 0, 0);
    }
    __syncthreads();   // epilogue barrier #1
    __syncthreads();   // epilogue barrier #2

#pragma unroll
    for (int g = 0; g < 4; ++g) {
      f32x4 lv = *(const f32x4*)(l_l + g * 16 + quad * 4);
      f32x4 li;
#pragma unroll
      for (int r = 0; r < 4; ++r) li[r] = 1.0f / lv[r];
#pragma unroll
      for (int cb = 0; cb < 8; ++cb)
#pragma unroll
        for (int r = 0; r < 4; ++r)
          out[((size_t)b * S_LEN + s0 + g * 16 + quad * 4 + r) * 512 + e0 + cb * 16 + l16] =
              acc[g][cb][r] * li[r];
    }
  }
}

// ---------------- host launch ----------------
extern "C" void kernel_launch(void* const* d_in, const int* in_sizes, int n_in,
                              void* d_out, int out_size, void* d_ws, size_t ws_size,
                              hipStream_t stream) {
  const float* x  = (const float*)d_in[0];
  const float* Wq = (const float*)d_in[1];
  const float* bq = (const float*)d_in[2];
  const float* Wk = (const float*)d_in[3];
  const float* bk = (const float*)d_in[4];
  const float* Wv = (const float*)d_in[5];
  const float* bv = (const float*)d_in[6];

  short* Wt  = (short*)d_ws;
  short* xb  = (short*)((char*)d_ws + 1572864);
  short* Qg  = xb + (size_t)8388608;
  short* Kg  = Qg + (size_t)8388608;
  short* VTg = Kg + (size_t)8388608;

  xconv_kernel<<<4096, 256, 0, stream>>>(x, xb);
  wconv_kernel<<<192, 256, 0, stream>>>(Wq, Wk, Wv, Wt);
  qkv_gemm<<<1536, 256, 0, stream>>>(xb, Wt, bq, bk, bv, Qg, Kg, VTg);
  attn_kernel<<<256, 512, 0, stream>>>(Qg, Kg, VTg, (float*)d_out);
}

// Round 10
// 215.513 us; speedup vs baseline: 1.2295x; 1.0183x over previous
//
#include <hip/hip_runtime.h>
#include <stdint.h>

// Self-attention, B=8 S=2048 D=E=512, fp32 in/out, bf16 MFMA internally.
//   xconv/wconv: unchanged.
//   qkv v3: unchanged (R9: pipelined + XCD-pinned m-partitioning).
//   attn v9: v8 (producer/consumer wave split, 102 µs) + PER-BLOCK K-TILE ROTATION:
//     block qt processes tiles in order (kt + qt*2) & 63. De-phases the 32 blocks
//     of each XCD so they don't hit the SAME 32KB K/V tile simultaneously
//     (L2 bank contention theory for the 3-4x gap over the LDS/critical-path
//     model). Valid because no-max softmax + acc are order-independent sums.

using f32x4 = __attribute__((ext_vector_type(4))) float;
using s16x8 = __attribute__((ext_vector_type(8))) short;
using u16x4 = __attribute__((ext_vector_type(4))) unsigned short;

#define S_LEN 2048
#define EMB   512

#define ASYNC16(g, l)                                                     \
  __builtin_amdgcn_global_load_lds(                                       \
      (const __attribute__((address_space(1))) void*)(g),                 \
      (__attribute__((address_space(3))) void*)(l), 16, 0, 0)

__device__ __forceinline__ unsigned short f2bf(float f) {
  union { float f; unsigned u; } v; v.f = f;
  unsigned r = v.u + 0x7fffu + ((v.u >> 16) & 1u);   // RNE
  return (unsigned short)(r >> 16);
}

// ---------------- kernel 0: x fp32 -> bf16 ----------------
__global__ __launch_bounds__(256) void xconv_kernel(
    const float* __restrict__ x, short* __restrict__ xb) {
  int i = (blockIdx.x * 256 + threadIdx.x) * 8;
  f32x4 a = *(const f32x4*)(x + i);
  f32x4 b = *(const f32x4*)(x + i + 4);
  s16x8 h;
  h[0] = (short)f2bf(a[0]); h[1] = (short)f2bf(a[1]);
  h[2] = (short)f2bf(a[2]); h[3] = (short)f2bf(a[3]);
  h[4] = (short)f2bf(b[0]); h[5] = (short)f2bf(b[1]);
  h[6] = (short)f2bf(b[2]); h[7] = (short)f2bf(b[3]);
  *(s16x8*)(xb + i) = h;
}

// ---------------- kernel 1: weight transpose (LDS-tiled, coalesced) ----------------
__global__ __launch_bounds__(256) void wconv_kernel(
    const float* __restrict__ Wq, const float* __restrict__ Wk,
    const float* __restrict__ Wv, short* __restrict__ Wt) {
  __shared__ float T[64][65];
  int bid = blockIdx.x;
  int mat = bid >> 6;
  int t   = bid & 63;
  int k0  = (t & 7) << 6, n0 = (t >> 3) << 6;
  const float* W = (mat == 0) ? Wq : (mat == 1) ? Wk : Wv;
  int tid = threadIdx.x;
  int rr = tid >> 4, cc = tid & 15;
#pragma unroll
  for (int p = 0; p < 4; ++p) {
    int row = p * 16 + rr;
    f32x4 v = *(const f32x4*)(W + (size_t)(k0 + row) * 512 + n0 + cc * 4);
#pragma unroll
    for (int j = 0; j < 4; ++j) T[row][cc * 4 + j] = v[j];
  }
  __syncthreads();
  short* D = Wt + (size_t)mat * 262144;
#pragma unroll
  for (int p = 0; p < 4; ++p) {
    int nrow = p * 16 + rr;
    u16x4 h;
#pragma unroll
    for (int j = 0; j < 4; ++j) h[j] = f2bf(T[cc * 4 + j][nrow]);
    *(u16x4*)(D + (size_t)(n0 + nrow) * 512 + k0 + cc * 4) = h;
  }
}

// ---------------- kernel 2: QKV projection GEMM (pipelined + XCD-pinned m) ----------------
__global__ __launch_bounds__(256) void qkv_gemm(
    const short* __restrict__ xb, const short* __restrict__ Wt,
    const float* __restrict__ bq, const float* __restrict__ bk,
    const float* __restrict__ bv,
    short* __restrict__ Qg, short* __restrict__ Kg, short* __restrict__ VTg) {
  __shared__ __align__(16) short As[2][128 * 64];
  __shared__ __align__(16) short Bs[2][128 * 64];
  int gid = blockIdx.x;
  int xcd = gid & 7;
  int s   = gid >> 3;
  int mt_l = s / 12;
  int j    = s - mt_l * 12;
  int mat  = j >> 2;
  int nt   = j & 3;
  int mt   = xcd * 16 + mt_l;
  int m0   = mt << 7, n0 = nt << 7;
  const short* W    = Wt + (size_t)mat * 262144;
  const float* bias = (mat == 0) ? bq : (mat == 1) ? bk : bv;

  int tid = threadIdx.x, lane = tid & 63, wv = tid >> 6;
  int l16 = lane & 15, quad = lane >> 4;
  int wr = (wv & 1) << 6, wc = (wv >> 1) << 6;
  int drow = lane >> 3;
  int dchk = (lane & 7) ^ drow;

  const short* asrc[4];
  const short* bsrc[4];
#pragma unroll
  for (int i = 0; i < 4; ++i) {
    int row = (wv * 4 + i) * 8 + drow;
    asrc[i] = xb + (size_t)(m0 + row) * 512 + dchk * 8;
    bsrc[i] = W  + (size_t)(n0 + row) * 512 + dchk * 8;
  }

  const f32x4 Z4 = {0.f, 0.f, 0.f, 0.f};
  f32x4 acc[4][4];
#pragma unroll
  for (int a = 0; a < 4; ++a)
#pragma unroll
    for (int c = 0; c < 4; ++c) acc[a][c] = Z4;

#pragma unroll
  for (int i = 0; i < 4; ++i) {
    int g = wv * 4 + i;
    ASYNC16(asrc[i], &As[0][g * 512]);
    ASYNC16(bsrc[i], &Bs[0][g * 512]);
  }
  __syncthreads();

  for (int it = 0; it < 8; ++it) {
    int buf = it & 1;
    if (it < 7) {
      int k1 = (it + 1) << 6;
#pragma unroll
      for (int i = 0; i < 4; ++i) {
        int g = wv * 4 + i;
        ASYNC16(asrc[i] + k1, &As[buf ^ 1][g * 512]);
        ASYNC16(bsrc[i] + k1, &Bs[buf ^ 1][g * 512]);
      }
    }
#pragma unroll
    for (int kk = 0; kk < 2; ++kk) {
      s16x8 af[4], bfr[4];
#pragma unroll
      for (int rb = 0; rb < 4; ++rb) {
        int row = wr + rb * 16 + l16;
        int c   = kk * 4 + quad;
        af[rb] = *(const s16x8*)(&As[buf][row * 64 + ((c ^ (row & 7)) * 8)]);
      }
#pragma unroll
      for (int cb = 0; cb < 4; ++cb) {
        int row = wc + cb * 16 + l16;
        int c   = kk * 4 + quad;
        bfr[cb] = *(const s16x8*)(&Bs[buf][row * 64 + ((c ^ (row & 7)) * 8)]);
      }
#pragma unroll
      for (int rb = 0; rb < 4; ++rb)
#pragma unroll
        for (int cb = 0; cb < 4; ++cb)
          acc[rb][cb] = __builtin_amdgcn_mfma_f32_16x16x32_bf16(af[rb], bfr[cb], acc[rb][cb], 0, 0, 0);
    }
    __syncthreads();
  }

  float bsv[4];
#pragma unroll
  for (int cb = 0; cb < 4; ++cb) bsv[cb] = bias[n0 + wc + cb * 16 + l16];

  if (mat < 2) {
    short* D = (mat == 0) ? Qg : Kg;
#pragma unroll
    for (int rb = 0; rb < 4; ++rb)
#pragma unroll
      for (int cb = 0; cb < 4; ++cb)
#pragma unroll
        for (int r = 0; r < 4; ++r) {
          int m = m0 + wr + rb * 16 + quad * 4 + r;
          D[(size_t)m * 512 + n0 + wc + cb * 16 + l16] =
              (short)f2bf(acc[rb][cb][r] + bsv[cb]);
        }
  } else {
#pragma unroll
    for (int rb = 0; rb < 4; ++rb)
#pragma unroll
      for (int cb = 0; cb < 4; ++cb) {
        u16x4 h;
#pragma unroll
        for (int r = 0; r < 4; ++r) h[r] = f2bf(acc[rb][cb][r] + bsv[cb]);
        int m  = m0 + wr + rb * 16 + quad * 4;
        int bb = m >> 11, sl = m & 2047;
        int e  = n0 + wc + cb * 16 + l16;
        size_t idx = ((((size_t)bb * 32 + (e >> 4)) * 64 + (sl >> 5)) * 16 +
                      (e & 15)) * 32 + (sl & 31);
        *(u16x4*)(VTg + idx) = h;
      }
  }
}

// ---------------- kernel 3: flash attention v9 (v8 + per-block tile rotation) ----------------
// Identical to v8 except: block qt walks K/V tiles in order phys = (kt + qt*2) & 63.
// Buffer parity (rbuf/wbuf, Pl[kt&1]) stays on LOGICAL kt; only addresses rotate.
// Softmax is no-max (plain sum) and acc accumulation is order-independent -> exact
// same math, different summation order (within fp tolerance).
__global__ __launch_bounds__(512, 2) void attn_kernel(
    const short* __restrict__ Qg, const short* __restrict__ Kg,
    const short* __restrict__ VTg, float* __restrict__ out) {
  __shared__ __align__(16) short Kt[3][32 * 512];   // 96 KB triple buffer
  __shared__ __align__(16) short Pl[2][64 * 40];    // 10 KB double buffer
  __shared__ float l_l[64];
  const float SCL2 = 0.06375871855f;  // log2(e)/sqrt(512)

  int b = blockIdx.x & 7, qt = blockIdx.x >> 3;   // qt 0..31
  int s0 = qt << 6;                                // 64 rows/block
  int rot = (qt << 1) & 63;                        // per-block tile phase
  int tid = threadIdx.x, lane = tid & 63, wv = tid >> 6;  // wv 0..7
  int l16 = lane & 15, quad = lane >> 4;

  const short* Kb = Kg  + (size_t)b * S_LEN * 512;
  const short* Vb = VTg + (size_t)b * 1048576;     // [32 et][64 st][16][32]

  const short* kdma[4];
#pragma unroll
  for (int i = 0; i < 4; ++i) {
    int r = wv * 4 + i;
    kdma[i] = Kb + (size_t)r * 512 + ((lane ^ (r & 7)) * 8);
  }

  // ---- prologue: stage K tiles phys(0), phys(1) ----
  {
    size_t a0 = (size_t)rot * 16384;
    size_t a1 = (size_t)((rot + 1) & 63) * 16384;
#pragma unroll
    for (int i = 0; i < 4; ++i)
      ASYNC16(kdma[i] + a0, &Kt[0][(wv * 4 + i) * 512]);
#pragma unroll
    for (int i = 0; i < 4; ++i)
      ASYNC16(kdma[i] + a1, &Kt[1][(wv * 4 + i) * 512]);
  }

  if (wv < 4) {
    // ================= QK producer branch =================
    int a = wv & 1, h = wv >> 1;
    const short* qrowA = Qg + ((size_t)b * S_LEN + s0 + a * 32 + l16) * 512 + quad * 8;
    const short* qrowB = qrowA + (size_t)16 * 512;
    s16x8 qfA[16], qfB[16];
#pragma unroll
    for (int c = 0; c < 16; ++c) {
      qfA[c] = *(const s16x8*)(qrowA + c * 32);
      qfB[c] = *(const s16x8*)(qrowB + c * 32);
    }
    const f32x4 Z4 = {0.f, 0.f, 0.f, 0.f};
    f32x4 lsumA = Z4, lsumB = Z4;

    __syncthreads();   // prologue drain  [barrier #0]

    for (int kt = 0; kt < 64; ++kt) {
      int rbuf = kt % 3, wbuf = (kt + 2) % 3;
      {
        size_t adv = (size_t)((kt + 2 + rot) & 63) * 16384;
#pragma unroll
        for (int i = 0; i < 4; ++i)
          ASYNC16(kdma[i] + adv, &Kt[wbuf][(wv * 4 + i) * 512]);
      }
      __builtin_amdgcn_sched_barrier(0);

      f32x4 sA = Z4, sB = Z4;
      int krow = h * 16 + l16;
      const short* kb = &Kt[rbuf][krow * 512];
      int ksw = krow & 7;
      __builtin_amdgcn_s_setprio(1);
#pragma unroll
      for (int c = 0; c < 16; ++c) {
        s16x8 kf = *(const s16x8*)(kb + (((c * 4 + quad) ^ ksw) * 8));
        sA = __builtin_amdgcn_mfma_f32_16x16x32_bf16(qfA[c], kf, sA, 0, 0, 0);
        sB = __builtin_amdgcn_mfma_f32_16x16x32_bf16(qfB[c], kf, sB, 0, 0, 0);
      }
      __builtin_amdgcn_s_setprio(0);

      short* Pc = Pl[kt & 1];
#pragma unroll
      for (int r = 0; r < 4; ++r) {
        float pA = exp2f(sA[r] * SCL2);
        lsumA[r] += pA;
        Pc[(a * 32 + quad * 4 + r) * 40 + h * 16 + l16] = (short)f2bf(pA);
        float pB = exp2f(sB[r] * SCL2);
        lsumB[r] += pB;
        Pc[(a * 32 + 16 + quad * 4 + r) * 40 + h * 16 + l16] = (short)f2bf(pB);
      }

      asm volatile("s_waitcnt vmcnt(4) lgkmcnt(0)\n\ts_barrier" ::: "memory");
      __builtin_amdgcn_sched_barrier(0);
    }

#pragma unroll
    for (int r = 0; r < 4; ++r) {
      float vA = lsumA[r];
      vA += __shfl_xor(vA, 1); vA += __shfl_xor(vA, 2);
      vA += __shfl_xor(vA, 4); vA += __shfl_xor(vA, 8);
      lsumA[r] = vA;
      float vB = lsumB[r];
      vB += __shfl_xor(vB, 1); vB += __shfl_xor(vB, 2);
      vB += __shfl_xor(vB, 4); vB += __shfl_xor(vB, 8);
      lsumB[r] = vB;
    }
    if (h == 0 && l16 == 0) {
#pragma unroll
      for (int r = 0; r < 4; ++r) {
        l_l[a * 32 + quad * 4 + r]      = lsumA[r];
        l_l[a * 32 + 16 + quad * 4 + r] = lsumB[r];
      }
    }
    __syncthreads();   // epilogue barrier #1
    if (h == 1 && l16 == 0) {
#pragma unroll
      for (int r = 0; r < 4; ++r) {
        l_l[a * 32 + quad * 4 + r]      += lsumA[r];
        l_l[a * 32 + 16 + quad * 4 + r] += lsumB[r];
      }
    }
    __syncthreads();   // epilogue barrier #2
  } else {
    // ================= PV consumer branch =================
    int pw = wv - 4;
    int e0 = pw << 7;
    const short* vbase = Vb + (size_t)pw * 262144 + l16 * 32 + quad * 8;

    const f32x4 Z4 = {0.f, 0.f, 0.f, 0.f};
    f32x4 acc[4][8];
#pragma unroll
    for (int g = 0; g < 4; ++g)
#pragma unroll
      for (int cb = 0; cb < 8; ++cb) acc[g][cb] = Z4;
    s16x8 vfA[8], vfB[8];

    __syncthreads();   // prologue drain  [barrier #0]

    for (int kt = 0; kt < 64; kt += 2) {
      {
        size_t adv = (size_t)((kt + 2 + rot) & 63) * 16384;
        int wbuf = (kt + 2) % 3;
#pragma unroll
        for (int i = 0; i < 4; ++i)
          ASYNC16(kdma[i] + adv, &Kt[wbuf][(wv * 4 + i) * 512]);
      }
      {
        size_t vadv = (size_t)((kt + rot) & 63) * 512;
#pragma unroll
        for (int cb = 0; cb < 8; ++cb)
          vfA[cb] = *(const s16x8*)(vbase + (size_t)cb * 32768 + vadv);
      }
      if (kt) {
        s16x8 pf[4];
#pragma unroll
        for (int g = 0; g < 4; ++g)
          pf[g] = *(const s16x8*)(&Pl[1][(g * 16 + l16) * 40 + quad * 8]);
        __builtin_amdgcn_s_setprio(1);
#pragma unroll
        for (int cb = 0; cb < 8; ++cb)
#pragma unroll
          for (int g = 0; g < 4; ++g)
            acc[g][cb] = __builtin_amdgcn_mfma_f32_16x16x32_bf16(pf[g], vfB[cb], acc[g][cb], 0, 0, 0);
        __builtin_amdgcn_s_setprio(0);
      }
      asm volatile("s_waitcnt lgkmcnt(0)\n\ts_barrier" ::: "memory");
      __builtin_amdgcn_sched_barrier(0);

      {
        size_t adv = (size_t)((kt + 3 + rot) & 63) * 16384;
        int wbuf = (kt + 3) % 3;
#pragma unroll
        for (int i = 0; i < 4; ++i)
          ASYNC16(kdma[i] + adv, &Kt[wbuf][(wv * 4 + i) * 512]);
      }
      {
        size_t vadv = (size_t)((kt + 1 + rot) & 63) * 512;
#pragma unroll
        for (int cb = 0; cb < 8; ++cb)
          vfB[cb] = *(const s16x8*)(vbase + (size_t)cb * 32768 + vadv);
      }
      {
        s16x8 pf[4];
#pragma unroll
        for (int g = 0; g < 4; ++g)
          pf[g] = *(const s16x8*)(&Pl[0][(g * 16 + l16) * 40 + quad * 8]);
        __builtin_amdgcn_s_setprio(1);
#pragma unroll
        for (int cb = 0; cb < 8; ++cb)
#pragma unroll
          for (int g = 0; g < 4; ++g)
            acc[g][cb] = __builtin_amdgcn_mfma_f32_16x16x32_bf16(pf[g], vfA[cb], acc[g][cb], 0, 0, 0);
        __builtin_amdgcn_s_setprio(0);
      }
      asm volatile("s_waitcnt lgkmcnt(0)\n\ts_barrier" ::: "memory");
      __builtin_amdgcn_sched_barrier(0);
    }

    asm volatile("s_waitcnt vmcnt(0)" ::: "memory");
    __builtin_amdgcn_sched_barrier(0);
    {
      s16x8 pf[4];
#pragma unroll
      for (int g = 0; g < 4; ++g)
        pf[g] = *(const s16x8*)(&Pl[1][(g * 16 + l16) * 40 + quad * 8]);
#pragma unroll
      for (int cb = 0; cb < 8; ++cb)
#pragma unroll
        for (int g = 0; g < 4; ++g)
          acc[g][cb] = __builtin_amdgcn_mfma_f32_16x16x32_bf16(pf[g], vfB[cb], acc[g][cb], 0, 0, 0);
    }
    __syncthreads();   // epilogue barrier #1
    __syncthreads();   // epilogue barrier #2

#pragma unroll
    for (int g = 0; g < 4; ++g) {
      f32x4 lv = *(const f32x4*)(l_l + g * 16 + quad * 4);
      f32x4 li;
#pragma unroll
      for (int r = 0; r < 4; ++r) li[r] = 1.0f / lv[r];
#pragma unroll
      for (int cb = 0; cb < 8; ++cb)
#pragma unroll
        for (int r = 0; r < 4; ++r)
          out[((size_t)b * S_LEN + s0 + g * 16 + quad * 4 + r) * 512 + e0 + cb * 16 + l16] =
              acc[g][cb][r] * li[r];
    }
  }
}

// ---------------- host launch ----------------
extern "C" void kernel_launch(void* const* d_in, const int* in_sizes, int n_in,
                              void* d_out, int out_size, void* d_ws, size_t ws_size,
                              hipStream_t stream) {
  const float* x  = (const float*)d_in[0];
  const float* Wq = (const float*)d_in[1];
  const float* bq = (const float*)d_in[2];
  const float* Wk = (const float*)d_in[3];
  const float* bk = (const float*)d_in[4];
  const float* Wv = (const float*)d_in[5];
  const float* bv = (const float*)d_in[6];

  short* Wt  = (short*)d_ws;
  short* xb  = (short*)((char*)d_ws + 1572864);
  short* Qg  = xb + (size_t)8388608;
  short* Kg  = Qg + (size_t)8388608;
  short* VTg = Kg + (size_t)8388608;

  xconv_kernel<<<4096, 256, 0, stream>>>(x, xb);
  wconv_kernel<<<192, 256, 0, stream>>>(Wq, Wk, Wv, Wt);
  qkv_gemm<<<1536, 256, 0, stream>>>(xb, Wt, bq, bk, bv, Qg, Kg, VTg);
  attn_kernel<<<256, 512, 0, stream>>>(Qg, Kg, VTg, (float*)d_out);
}

// Round 11
// 212.474 us; speedup vs baseline: 1.2471x; 1.0143x over previous
//
#include <hip/hip_runtime.h>
#include <stdint.h>

// Self-attention, B=8 S=2048 D=E=512, fp32 in/out, bf16 MFMA internally.
//   xconv/wconv: unchanged.
//   qkv v4: R9 (pipelined + XCD-pinned) + LDS-TRANSPOSED Q/K EPILOGUE:
//     acc -> swizzled 128x128 bf16 tile in the dead As buffer -> coalesced
//     s16x8 stores (256B full-line segments). Replaces 64 scalar 2B stores/thread
//     (16x fewer store instrs, no partial-line L2 write-allocate).
//   attn v9: unchanged (measured 99.5 µs) — control row.

using f32x4 = __attribute__((ext_vector_type(4))) float;
using s16x8 = __attribute__((ext_vector_type(8))) short;
using u16x4 = __attribute__((ext_vector_type(4))) unsigned short;

#define S_LEN 2048
#define EMB   512

#define ASYNC16(g, l)                                                     \
  __builtin_amdgcn_global_load_lds(                                       \
      (const __attribute__((address_space(1))) void*)(g),                 \
      (__attribute__((address_space(3))) void*)(l), 16, 0, 0)

__device__ __forceinline__ unsigned short f2bf(float f) {
  union { float f; unsigned u; } v; v.f = f;
  unsigned r = v.u + 0x7fffu + ((v.u >> 16) & 1u);   // RNE
  return (unsigned short)(r >> 16);
}

// ---------------- kernel 0: x fp32 -> bf16 ----------------
__global__ __launch_bounds__(256) void xconv_kernel(
    const float* __restrict__ x, short* __restrict__ xb) {
  int i = (blockIdx.x * 256 + threadIdx.x) * 8;
  f32x4 a = *(const f32x4*)(x + i);
  f32x4 b = *(const f32x4*)(x + i + 4);
  s16x8 h;
  h[0] = (short)f2bf(a[0]); h[1] = (short)f2bf(a[1]);
  h[2] = (short)f2bf(a[2]); h[3] = (short)f2bf(a[3]);
  h[4] = (short)f2bf(b[0]); h[5] = (short)f2bf(b[1]);
  h[6] = (short)f2bf(b[2]); h[7] = (short)f2bf(b[3]);
  *(s16x8*)(xb + i) = h;
}

// ---------------- kernel 1: weight transpose (LDS-tiled, coalesced) ----------------
__global__ __launch_bounds__(256) void wconv_kernel(
    const float* __restrict__ Wq, const float* __restrict__ Wk,
    const float* __restrict__ Wv, short* __restrict__ Wt) {
  __shared__ float T[64][65];
  int bid = blockIdx.x;
  int mat = bid >> 6;
  int t   = bid & 63;
  int k0  = (t & 7) << 6, n0 = (t >> 3) << 6;
  const float* W = (mat == 0) ? Wq : (mat == 1) ? Wk : Wv;
  int tid = threadIdx.x;
  int rr = tid >> 4, cc = tid & 15;
#pragma unroll
  for (int p = 0; p < 4; ++p) {
    int row = p * 16 + rr;
    f32x4 v = *(const f32x4*)(W + (size_t)(k0 + row) * 512 + n0 + cc * 4);
#pragma unroll
    for (int j = 0; j < 4; ++j) T[row][cc * 4 + j] = v[j];
  }
  __syncthreads();
  short* D = Wt + (size_t)mat * 262144;
#pragma unroll
  for (int p = 0; p < 4; ++p) {
    int nrow = p * 16 + rr;
    u16x4 h;
#pragma unroll
    for (int j = 0; j < 4; ++j) h[j] = f2bf(T[cc * 4 + j][nrow]);
    *(u16x4*)(D + (size_t)(n0 + nrow) * 512 + k0 + cc * 4) = h;
  }
}

// ---------------- kernel 2: QKV projection GEMM (pipelined + XCD-pinned + LDS epilogue) ----------------
__global__ __launch_bounds__(256) void qkv_gemm(
    const short* __restrict__ xb, const short* __restrict__ Wt,
    const float* __restrict__ bq, const float* __restrict__ bk,
    const float* __restrict__ bv,
    short* __restrict__ Qg, short* __restrict__ Kg, short* __restrict__ VTg) {
  __shared__ __align__(16) short As[2][128 * 64];
  __shared__ __align__(16) short Bs[2][128 * 64];
  int gid = blockIdx.x;
  int xcd = gid & 7;
  int s   = gid >> 3;
  int mt_l = s / 12;
  int j    = s - mt_l * 12;
  int mat  = j >> 2;
  int nt   = j & 3;
  int mt   = xcd * 16 + mt_l;
  int m0   = mt << 7, n0 = nt << 7;
  const short* W    = Wt + (size_t)mat * 262144;
  const float* bias = (mat == 0) ? bq : (mat == 1) ? bk : bv;

  int tid = threadIdx.x, lane = tid & 63, wv = tid >> 6;
  int l16 = lane & 15, quad = lane >> 4;
  int wr = (wv & 1) << 6, wc = (wv >> 1) << 6;
  int drow = lane >> 3;
  int dchk = (lane & 7) ^ drow;

  const short* asrc[4];
  const short* bsrc[4];
#pragma unroll
  for (int i = 0; i < 4; ++i) {
    int row = (wv * 4 + i) * 8 + drow;
    asrc[i] = xb + (size_t)(m0 + row) * 512 + dchk * 8;
    bsrc[i] = W  + (size_t)(n0 + row) * 512 + dchk * 8;
  }

  const f32x4 Z4 = {0.f, 0.f, 0.f, 0.f};
  f32x4 acc[4][4];
#pragma unroll
  for (int a = 0; a < 4; ++a)
#pragma unroll
    for (int c = 0; c < 4; ++c) acc[a][c] = Z4;

#pragma unroll
  for (int i = 0; i < 4; ++i) {
    int g = wv * 4 + i;
    ASYNC16(asrc[i], &As[0][g * 512]);
    ASYNC16(bsrc[i], &Bs[0][g * 512]);
  }
  __syncthreads();

  for (int it = 0; it < 8; ++it) {
    int buf = it & 1;
    if (it < 7) {
      int k1 = (it + 1) << 6;
#pragma unroll
      for (int i = 0; i < 4; ++i) {
        int g = wv * 4 + i;
        ASYNC16(asrc[i] + k1, &As[buf ^ 1][g * 512]);
        ASYNC16(bsrc[i] + k1, &Bs[buf ^ 1][g * 512]);
      }
    }
#pragma unroll
    for (int kk = 0; kk < 2; ++kk) {
      s16x8 af[4], bfr[4];
#pragma unroll
      for (int rb = 0; rb < 4; ++rb) {
        int row = wr + rb * 16 + l16;
        int c   = kk * 4 + quad;
        af[rb] = *(const s16x8*)(&As[buf][row * 64 + ((c ^ (row & 7)) * 8)]);
      }
#pragma unroll
      for (int cb = 0; cb < 4; ++cb) {
        int row = wc + cb * 16 + l16;
        int c   = kk * 4 + quad;
        bfr[cb] = *(const s16x8*)(&Bs[buf][row * 64 + ((c ^ (row & 7)) * 8)]);
      }
#pragma unroll
      for (int rb = 0; rb < 4; ++rb)
#pragma unroll
        for (int cb = 0; cb < 4; ++cb)
          acc[rb][cb] = __builtin_amdgcn_mfma_f32_16x16x32_bf16(af[rb], bfr[cb], acc[rb][cb], 0, 0, 0);
    }
    __syncthreads();   // final iter's barrier also fences As reads before Ct reuse
  }

  float bsv[4];
#pragma unroll
  for (int cb = 0; cb < 4; ++cb) bsv[cb] = bias[n0 + wc + cb * 16 + l16];

  if (mat < 2) {
    // LDS-transposed epilogue: acc -> swizzled 128x128 bf16 tile in dead As,
    // then coalesced s16x8 stores (4 rows x 256B full-line segments per wave-op).
    short* D  = (mat == 0) ? Qg : Kg;
    short* Ct = &As[0][0];   // 32 KB, exactly 128x128 bf16
#pragma unroll
    for (int rb = 0; rb < 4; ++rb)
#pragma unroll
      for (int cb = 0; cb < 4; ++cb)
#pragma unroll
        for (int r = 0; r < 4; ++r) {
          int m_l = wr + rb * 16 + quad * 4 + r;
          int e_l = wc + cb * 16 + l16;
          int cc  = e_l >> 3;
          Ct[m_l * 128 + ((cc ^ (m_l & 7)) * 8) + (e_l & 7)] =
              (short)f2bf(acc[rb][cb][r] + bsv[cb]);
        }
    __syncthreads();
    // wave wv owns rows [wv*32, wv*32+32): lane -> (row += lane>>4, chunk = lane&15)
#pragma unroll
    for (int g = 0; g < 8; ++g) {
      int row = wv * 32 + g * 4 + (lane >> 4);
      int cc  = lane & 15;
      s16x8 v = *(const s16x8*)(Ct + row * 128 + ((cc ^ (row & 7)) * 8));
      *(s16x8*)(D + (size_t)(m0 + row) * 512 + n0 + cc * 8) = v;
    }
  } else {
#pragma unroll
    for (int rb = 0; rb < 4; ++rb)
#pragma unroll
      for (int cb = 0; cb < 4; ++cb) {
        u16x4 h;
#pragma unroll
        for (int r = 0; r < 4; ++r) h[r] = f2bf(acc[rb][cb][r] + bsv[cb]);
        int m  = m0 + wr + rb * 16 + quad * 4;
        int bb = m >> 11, sl = m & 2047;
        int e  = n0 + wc + cb * 16 + l16;
        size_t idx = ((((size_t)bb * 32 + (e >> 4)) * 64 + (sl >> 5)) * 16 +
                      (e & 15)) * 32 + (sl & 31);
        *(u16x4*)(VTg + idx) = h;
      }
  }
}

// ---------------- kernel 3: flash attention v9 (UNCHANGED, 99.5 µs control) ----------------
__global__ __launch_bounds__(512, 2) void attn_kernel(
    const short* __restrict__ Qg, const short* __restrict__ Kg,
    const short* __restrict__ VTg, float* __restrict__ out) {
  __shared__ __align__(16) short Kt[3][32 * 512];   // 96 KB triple buffer
  __shared__ __align__(16) short Pl[2][64 * 40];    // 10 KB double buffer
  __shared__ float l_l[64];
  const float SCL2 = 0.06375871855f;  // log2(e)/sqrt(512)

  int b = blockIdx.x & 7, qt = blockIdx.x >> 3;   // qt 0..31
  int s0 = qt << 6;                                // 64 rows/block
  int rot = (qt << 1) & 63;                        // per-block tile phase
  int tid = threadIdx.x, lane = tid & 63, wv = tid >> 6;  // wv 0..7
  int l16 = lane & 15, quad = lane >> 4;

  const short* Kb = Kg  + (size_t)b * S_LEN * 512;
  const short* Vb = VTg + (size_t)b * 1048576;     // [32 et][64 st][16][32]

  const short* kdma[4];
#pragma unroll
  for (int i = 0; i < 4; ++i) {
    int r = wv * 4 + i;
    kdma[i] = Kb + (size_t)r * 512 + ((lane ^ (r & 7)) * 8);
  }

  {
    size_t a0 = (size_t)rot * 16384;
    size_t a1 = (size_t)((rot + 1) & 63) * 16384;
#pragma unroll
    for (int i = 0; i < 4; ++i)
      ASYNC16(kdma[i] + a0, &Kt[0][(wv * 4 + i) * 512]);
#pragma unroll
    for (int i = 0; i < 4; ++i)
      ASYNC16(kdma[i] + a1, &Kt[1][(wv * 4 + i) * 512]);
  }

  if (wv < 4) {
    // ================= QK producer branch =================
    int a = wv & 1, h = wv >> 1;
    const short* qrowA = Qg + ((size_t)b * S_LEN + s0 + a * 32 + l16) * 512 + quad * 8;
    const short* qrowB = qrowA + (size_t)16 * 512;
    s16x8 qfA[16], qfB[16];
#pragma unroll
    for (int c = 0; c < 16; ++c) {
      qfA[c] = *(const s16x8*)(qrowA + c * 32);
      qfB[c] = *(const s16x8*)(qrowB + c * 32);
    }
    const f32x4 Z4 = {0.f, 0.f, 0.f, 0.f};
    f32x4 lsumA = Z4, lsumB = Z4;

    __syncthreads();   // prologue drain  [barrier #0]

    for (int kt = 0; kt < 64; ++kt) {
      int rbuf = kt % 3, wbuf = (kt + 2) % 3;
      {
        size_t adv = (size_t)((kt + 2 + rot) & 63) * 16384;
#pragma unroll
        for (int i = 0; i < 4; ++i)
          ASYNC16(kdma[i] + adv, &Kt[wbuf][(wv * 4 + i) * 512]);
      }
      __builtin_amdgcn_sched_barrier(0);

      f32x4 sA = Z4, sB = Z4;
      int krow = h * 16 + l16;
      const short* kb = &Kt[rbuf][krow * 512];
      int ksw = krow & 7;
      __builtin_amdgcn_s_setprio(1);
#pragma unroll
      for (int c = 0; c < 16; ++c) {
        s16x8 kf = *(const s16x8*)(kb + (((c * 4 + quad) ^ ksw) * 8));
        sA = __builtin_amdgcn_mfma_f32_16x16x32_bf16(qfA[c], kf, sA, 0, 0, 0);
        sB = __builtin_amdgcn_mfma_f32_16x16x32_bf16(qfB[c], kf, sB, 0, 0, 0);
      }
      __builtin_amdgcn_s_setprio(0);

      short* Pc = Pl[kt & 1];
#pragma unroll
      for (int r = 0; r < 4; ++r) {
        float pA = exp2f(sA[r] * SCL2);
        lsumA[r] += pA;
        Pc[(a * 32 + quad * 4 + r) * 40 + h * 16 + l16] = (short)f2bf(pA);
        float pB = exp2f(sB[r] * SCL2);
        lsumB[r] += pB;
        Pc[(a * 32 + 16 + quad * 4 + r) * 40 + h * 16 + l16] = (short)f2bf(pB);
      }

      asm volatile("s_waitcnt vmcnt(4) lgkmcnt(0)\n\ts_barrier" ::: "memory");
      __builtin_amdgcn_sched_barrier(0);
    }

#pragma unroll
    for (int r = 0; r < 4; ++r) {
      float vA = lsumA[r];
      vA += __shfl_xor(vA, 1); vA += __shfl_xor(vA, 2);
      vA += __shfl_xor(vA, 4); vA += __shfl_xor(vA, 8);
      lsumA[r] = vA;
      float vB = lsumB[r];
      vB += __shfl_xor(vB, 1); vB += __shfl_xor(vB, 2);
      vB += __shfl_xor(vB, 4); vB += __shfl_xor(vB, 8);
      lsumB[r] = vB;
    }
    if (h == 0 && l16 == 0) {
#pragma unroll
      for (int r = 0; r < 4; ++r) {
        l_l[a * 32 + quad * 4 + r]      = lsumA[r];
        l_l[a * 32 + 16 + quad * 4 + r] = lsumB[r];
      }
    }
    __syncthreads();   // epilogue barrier #1
    if (h == 1 && l16 == 0) {
#pragma unroll
      for (int r = 0; r < 4; ++r) {
        l_l[a * 32 + quad * 4 + r]      += lsumA[r];
        l_l[a * 32 + 16 + quad * 4 + r] += lsumB[r];
      }
    }
    __syncthreads();   // epilogue barrier #2
  } else {
    // ================= PV consumer branch =================
    int pw = wv - 4;
    int e0 = pw << 7;
    const short* vbase = Vb + (size_t)pw * 262144 + l16 * 32 + quad * 8;

    const f32x4 Z4 = {0.f, 0.f, 0.f, 0.f};
    f32x4 acc[4][8];
#pragma unroll
    for (int g = 0; g < 4; ++g)
#pragma unroll
      for (int cb = 0; cb < 8; ++cb) acc[g][cb] = Z4;
    s16x8 vfA[8], vfB[8];

    __syncthreads();   // prologue drain  [barrier #0]

    for (int kt = 0; kt < 64; kt += 2) {
      {
        size_t adv = (size_t)((kt + 2 + rot) & 63) * 16384;
        int wbuf = (kt + 2) % 3;
#pragma unroll
        for (int i = 0; i < 4; ++i)
          ASYNC16(kdma[i] + adv, &Kt[wbuf][(wv * 4 + i) * 512]);
      }
      {
        size_t vadv = (size_t)((kt + rot) & 63) * 512;
#pragma unroll
        for (int cb = 0; cb < 8; ++cb)
          vfA[cb] = *(const s16x8*)(vbase + (size_t)cb * 32768 + vadv);
      }
      if (kt) {
        s16x8 pf[4];
#pragma unroll
        for (int g = 0; g < 4; ++g)
          pf[g] = *(const s16x8*)(&Pl[1][(g * 16 + l16) * 40 + quad * 8]);
        __builtin_amdgcn_s_setprio(1);
#pragma unroll
        for (int cb = 0; cb < 8; ++cb)
#pragma unroll
          for (int g = 0; g < 4; ++g)
            acc[g][cb] = __builtin_amdgcn_mfma_f32_16x16x32_bf16(pf[g], vfB[cb], acc[g][cb], 0, 0, 0);
        __builtin_amdgcn_s_setprio(0);
      }
      asm volatile("s_waitcnt lgkmcnt(0)\n\ts_barrier" ::: "memory");
      __builtin_amdgcn_sched_barrier(0);

      {
        size_t adv = (size_t)((kt + 3 + rot) & 63) * 16384;
        int wbuf = (kt + 3) % 3;
#pragma unroll
        for (int i = 0; i < 4; ++i)
          ASYNC16(kdma[i] + adv, &Kt[wbuf][(wv * 4 + i) * 512]);
      }
      {
        size_t vadv = (size_t)((kt + 1 + rot) & 63) * 512;
#pragma unroll
        for (int cb = 0; cb < 8; ++cb)
          vfB[cb] = *(const s16x8*)(vbase + (size_t)cb * 32768 + vadv);
      }
      {
        s16x8 pf[4];
#pragma unroll
        for (int g = 0; g < 4; ++g)
          pf[g] = *(const s16x8*)(&Pl[0][(g * 16 + l16) * 40 + quad * 8]);
        __builtin_amdgcn_s_setprio(1);
#pragma unroll
        for (int cb = 0; cb < 8; ++cb)
#pragma unroll
          for (int g = 0; g < 4; ++g)
            acc[g][cb] = __builtin_amdgcn_mfma_f32_16x16x32_bf16(pf[g], vfA[cb], acc[g][cb], 0, 0, 0);
        __builtin_amdgcn_s_setprio(0);
      }
      asm volatile("s_waitcnt lgkmcnt(0)\n\ts_barrier" ::: "memory");
      __builtin_amdgcn_sched_barrier(0);
    }

    asm volatile("s_waitcnt vmcnt(0)" ::: "memory");
    __builtin_amdgcn_sched_barrier(0);
    {
      s16x8 pf[4];
#pragma unroll
      for (int g = 0; g < 4; ++g)
        pf[g] = *(const s16x8*)(&Pl[1][(g * 16 + l16) * 40 + quad * 8]);
#pragma unroll
      for (int cb = 0; cb < 8; ++cb)
#pragma unroll
        for (int g = 0; g < 4; ++g)
          acc[g][cb] = __builtin_amdgcn_mfma_f32_16x16x32_bf16(pf[g], vfB[cb], acc[g][cb], 0, 0, 0);
    }
    __syncthreads();   // epilogue barrier #1
    __syncthreads();   // epilogue barrier #2

#pragma unroll
    for (int g = 0; g < 4; ++g) {
      f32x4 lv = *(const f32x4*)(l_l + g * 16 + quad * 4);
      f32x4 li;
#pragma unroll
      for (int r = 0; r < 4; ++r) li[r] = 1.0f / lv[r];
#pragma unroll
      for (int cb = 0; cb < 8; ++cb)
#pragma unroll
        for (int r = 0; r < 4; ++r)
          out[((size_t)b * S_LEN + s0 + g * 16 + quad * 4 + r) * 512 + e0 + cb * 16 + l16] =
              acc[g][cb][r] * li[r];
    }
  }
}

// ---------------- host launch ----------------
extern "C" void kernel_launch(void* const* d_in, const int* in_sizes, int n_in,
                              void* d_out, int out_size, void* d_ws, size_t ws_size,
                              hipStream_t stream) {
  const float* x  = (const float*)d_in[0];
  const float* Wq = (const float*)d_in[1];
  const float* bq = (const float*)d_in[2];
  const float* Wk = (const float*)d_in[3];
  const float* bk = (const float*)d_in[4];
  const float* Wv = (const float*)d_in[5];
  const float* bv = (const float*)d_in[6];

  short* Wt  = (short*)d_ws;
  short* xb  = (short*)((char*)d_ws + 1572864);
  short* Qg  = xb + (size_t)8388608;
  short* Kg  = Qg + (size_t)8388608;
  short* VTg = Kg + (size_t)8388608;

  xconv_kernel<<<4096, 256, 0, stream>>>(x, xb);
  wconv_kernel<<<192, 256, 0, stream>>>(Wq, Wk, Wv, Wt);
  qkv_gemm<<<1536, 256, 0, stream>>>(xb, Wt, bq, bk, bv, Qg, Kg, VTg);
  attn_kernel<<<256, 512, 0, stream>>>(Qg, Kg, VTg, (float*)d_out);
}